// Round 1
// baseline (1541.166 us; speedup 1.0000x reference)
//
#include <hip/hip_runtime.h>
#include <math.h>

#define T_STEPS 4
#define NN 20000
#define EE 160000
#define IND 64
#define DD 128
#define G3 384     // 3*D (GRU gates)
#define QS 512     // q|k|v|skip fused width

// ---------------------------------------------------------------------------
// Generic fp32 tiled GEMM: C[M,N] = A[M,K] @ B[K,N] + bias[N]
// B is row-major [K,N]. BM=BN=64, BK=16, 256 threads, 4x4 per thread.
// ---------------------------------------------------------------------------
#define BM 64
#define BN 64
#define BK 16

__global__ __launch_bounds__(256) void gemm_f32(
    const float* __restrict__ A, const float* __restrict__ B,
    const float* __restrict__ bias, float* __restrict__ C,
    int M, int N, int K)
{
  __shared__ float As[BK][BM + 1];
  __shared__ float Bs[BK][BN + 1];
  const int bm = blockIdx.y * BM;
  const int bn = blockIdx.x * BN;
  const int tid = threadIdx.x;
  const int tr = tid >> 4;   // 0..15
  const int tc = tid & 15;   // 0..15
  float acc[4][4] = {};
  for (int k0 = 0; k0 < K; k0 += BK) {
    for (int i = tid; i < BM * BK; i += 256) {
      int r = i >> 4;          // / BK
      int c = i & (BK - 1);
      int gr = bm + r;
      As[c][r] = (gr < M) ? A[(size_t)gr * K + (k0 + c)] : 0.f;
    }
    for (int i = tid; i < BK * BN; i += 256) {
      int r = i >> 6;          // / BN
      int c = i & (BN - 1);
      Bs[r][c] = B[(size_t)(k0 + r) * N + (bn + c)];
    }
    __syncthreads();
#pragma unroll
    for (int kk = 0; kk < BK; ++kk) {
      float a[4], b[4];
#pragma unroll
      for (int u = 0; u < 4; ++u) a[u] = As[kk][tr * 4 + u];
#pragma unroll
      for (int u = 0; u < 4; ++u) b[u] = Bs[kk][tc * 4 + u];
#pragma unroll
      for (int x = 0; x < 4; ++x)
#pragma unroll
        for (int y = 0; y < 4; ++y)
          acc[x][y] = fmaf(a[x], b[y], acc[x][y]);
    }
    __syncthreads();
  }
  const int gc0 = bn + tc * 4;
  float b0 = bias[gc0 + 0], b1 = bias[gc0 + 1], b2 = bias[gc0 + 2], b3 = bias[gc0 + 3];
#pragma unroll
  for (int x = 0; x < 4; ++x) {
    int gr = bm + tr * 4 + x;
    if (gr >= M) continue;
    float4 o = make_float4(acc[x][0] + b0, acc[x][1] + b1, acc[x][2] + b2, acc[x][3] + b3);
    *(float4*)&C[(size_t)gr * N + gc0] = o;
  }
}

// ---------------------------------------------------------------------------
// Weight packing: W_ih^T [64,384], W_hh^T [128,384], Wcat[l][128,512]=(q|k|v|skip),
// bcat[l][512]
// ---------------------------------------------------------------------------
__global__ void pack_weights(
    const float* __restrict__ Wih, const float* __restrict__ Whh,
    const float* __restrict__ Wq, const float* __restrict__ Wk,
    const float* __restrict__ Wv, const float* __restrict__ Ws,
    const float* __restrict__ bq, const float* __restrict__ bk,
    const float* __restrict__ bv, const float* __restrict__ bs,
    float* __restrict__ Bih, float* __restrict__ Bhh,
    float* __restrict__ Wcat, float* __restrict__ bcat)
{
  int gid = blockIdx.x * 256 + threadIdx.x;
  const int n1 = IND * G3;          // 24576
  const int n2 = DD * G3;           // 49152
  const int n3 = 2 * DD * QS;       // 131072
  const int n4 = 2 * QS;            // 1024
  if (gid < n1) { int k = gid / G3, j = gid % G3; Bih[gid] = Wih[j * IND + k]; return; }
  gid -= n1;
  if (gid < n2) { int k = gid / G3, j = gid % G3; Bhh[gid] = Whh[j * DD + k]; return; }
  gid -= n2;
  if (gid < n3) {
    int l = gid / (DD * QS);
    int rem = gid % (DD * QS);
    int k = rem / QS, n = rem % QS;
    const float* W = (n < 128) ? Wq : (n < 256) ? Wk : (n < 384) ? Wv : Ws;
    Wcat[gid] = W[l * DD * DD + k * DD + (n & 127)];
    return;
  }
  gid -= n3;
  if (gid < n4) {
    int l = gid / QS, n = gid % QS;
    const float* b = (n < 128) ? bq : (n < 256) ? bk : (n < 384) ? bv : bs;
    bcat[gid] = b[l * DD + (n & 127)];
  }
}

// ---------------------------------------------------------------------------
// CSR build (by destination), per timestep
// ---------------------------------------------------------------------------
__global__ void csr_count(const int* __restrict__ ei, int* __restrict__ deg)
{
  int gid = blockIdx.x * 256 + threadIdx.x;
  if (gid >= T_STEPS * EE) return;
  int t = gid / EE, e = gid % EE;
  int dst = ei[(size_t)t * 2 * EE + EE + e];
  atomicAdd(&deg[t * NN + dst], 1);
}

__global__ void csr_scan(const int* __restrict__ deg, int* __restrict__ offs,
                         int* __restrict__ cur)
{
  const int t = blockIdx.x;
  const int tid = threadIdx.x;
  __shared__ int s[256];
  int running = 0;
  for (int base = 0; base < NN; base += 256) {
    const int i = base + tid;
    const int v = (i < NN) ? deg[t * NN + i] : 0;
    s[tid] = v;
    __syncthreads();
    for (int o = 1; o < 256; o <<= 1) {
      int x = (tid >= o) ? s[tid - o] : 0;
      __syncthreads();
      if (tid >= o) s[tid] += x;
      __syncthreads();
    }
    const int excl = s[tid] - v;
    if (i < NN) {
      offs[t * (NN + 1) + i] = running + excl;
      cur[t * NN + i] = running + excl;
    }
    running += s[255];
    __syncthreads();
  }
  if (tid == 0) offs[t * (NN + 1) + NN] = running;
}

__global__ void csr_fill(const int* __restrict__ ei, const float* __restrict__ ea,
                         int* __restrict__ cur, int* __restrict__ csrc,
                         float* __restrict__ ca)
{
  int gid = blockIdx.x * 256 + threadIdx.x;
  if (gid >= T_STEPS * EE) return;
  int t = gid / EE, e = gid % EE;
  int src = ei[(size_t)t * 2 * EE + e];
  int dst = ei[(size_t)t * 2 * EE + EE + e];
  int slot = atomicAdd(&cur[t * NN + dst], 1);
  csrc[t * EE + slot] = src;
  ca[t * EE + slot] = ea[(size_t)t * EE + e];
}

// ---------------------------------------------------------------------------
// GRU gate fusion: h_new = (1-z)*tanh(i_n + r*h_n) + z*h ; writes h and h_all[t]
// ---------------------------------------------------------------------------
__global__ __launch_bounds__(256) void gru_gate(
    const float* __restrict__ gi, const float* __restrict__ gh,
    float* __restrict__ h, float* __restrict__ hall_t)
{
  int idx = blockIdx.x * 256 + threadIdx.x;   // exact NN*DD grid
  int n = idx >> 7, d = idx & 127;
  size_t gb = (size_t)n * G3 + d;
  float ir = gi[gb], iz = gi[gb + DD], inn = gi[gb + 2 * DD];
  float hr = gh[gb], hz = gh[gb + DD], hn = gh[gb + 2 * DD];
  float r = 1.f / (1.f + __expf(-(ir + hr)));
  float z = 1.f / (1.f + __expf(-(iz + hz)));
  float nv = tanhf(inn + r * hn);
  float hp = h[idx];
  float hnew = (1.f - z) * nv + z * hp;
  h[idx] = hnew;
  hall_t[idx] = hnew;
}

// ---------------------------------------------------------------------------
// Fused TransformerConv (d=128): one wave per dst node, online softmax over
// incoming edges, + skip + leaky_relu. qkvs row = [q(128)|k(128)|v(128)|skip(128)]
// ---------------------------------------------------------------------------
__global__ __launch_bounds__(256) void attn_conv(
    const float* __restrict__ qkvs,   // [NN,512]
    const int* __restrict__ offs,     // [NN+1]
    const int* __restrict__ csrc,     // [E]
    const float* __restrict__ ca,     // [E]
    const float* __restrict__ We,     // [128]
    float* __restrict__ hout)         // [NN,128]
{
  const int wv = (blockIdx.x * 256 + threadIdx.x) >> 6;
  const int lane = threadIdx.x & 63;
  if (wv >= NN) return;
  const float scale = 0.08838834764831845f;   // 1/sqrt(128)
  const float2 q  = *(const float2*)&qkvs[(size_t)wv * QS + 2 * lane];
  const float2 w2 = *(const float2*)&We[2 * lane];
  float qwe = q.x * w2.x + q.y * w2.y;
#pragma unroll
  for (int o = 1; o < 64; o <<= 1) qwe += __shfl_xor(qwe, o);
  const int e0 = offs[wv], e1 = offs[wv + 1];
  float m_run = -INFINITY, l_run = 0.f;
  float accx = 0.f, accy = 0.f;
  for (int base = e0; base < e1; base += 64) {
    const int cnt = min(64, e1 - base);
    int msrc = 0; float ma = 0.f;
    if (lane < cnt) { msrc = csrc[base + lane]; ma = ca[base + lane]; }
    float malpha = -INFINITY;
    for (int j = 0; j < cnt; ++j) {
      const int s = __shfl(msrc, j);
      const float a = __shfl(ma, j);
      const float2 k2 = *(const float2*)&qkvs[(size_t)s * QS + 128 + 2 * lane];
      float p = q.x * k2.x + q.y * k2.y;
#pragma unroll
      for (int o = 1; o < 64; o <<= 1) p += __shfl_xor(p, o);
      const float alpha = (p + a * qwe) * scale;
      if (lane == j) malpha = alpha;
    }
    float cm = malpha;
#pragma unroll
    for (int o = 1; o < 64; o <<= 1) cm = fmaxf(cm, __shfl_xor(cm, o));
    const float m_new = fmaxf(m_run, cm);
    const float fac = __expf(m_run - m_new);   // exp(-inf)=0 on first chunk
    const float ex = (lane < cnt) ? __expf(malpha - m_new) : 0.f;
    float sx = ex;
#pragma unroll
    for (int o = 1; o < 64; o <<= 1) sx += __shfl_xor(sx, o);
    l_run = l_run * fac + sx;
    accx *= fac; accy *= fac;
    for (int j = 0; j < cnt; ++j) {
      const int s = __shfl(msrc, j);
      const float a = __shfl(ma, j);
      const float w = __shfl(ex, j);
      const float2 v2 = *(const float2*)&qkvs[(size_t)s * QS + 256 + 2 * lane];
      accx += w * (v2.x + a * w2.x);
      accy += w * (v2.y + a * w2.y);
    }
    m_run = m_new;
  }
  const float inv = 1.f / (l_run + 1e-16f);
  const float2 sk = *(const float2*)&qkvs[(size_t)wv * QS + 384 + 2 * lane];
  float ox = accx * inv + sk.x;
  float oy = accy * inv + sk.y;
  ox = (ox > 0.f) ? ox : 0.01f * ox;   // leaky_relu
  oy = (oy > 0.f) ? oy : 0.01f * oy;
  *(float2*)&hout[(size_t)wv * DD + 2 * lane] = make_float2(ox, oy);
}

// ---------------------------------------------------------------------------
// mean over T
// ---------------------------------------------------------------------------
__global__ void mean_k(const float* __restrict__ hall, float* __restrict__ hm)
{
  int i = blockIdx.x * 256 + threadIdx.x;   // exact NN*DD grid
  float v = hall[i] + hall[i + NN * DD] + hall[i + 2 * NN * DD] + hall[i + 3 * NN * DD];
  hm[i] = 0.25f * v;
}

// ---------------------------------------------------------------------------
// Output conv projections: q1/k1/v1/s1 = h@W + b  (scalar per node)
// ---------------------------------------------------------------------------
__global__ __launch_bounds__(256) void out_proj(
    const float* __restrict__ h,
    const float* __restrict__ Wq, const float* __restrict__ Wk,
    const float* __restrict__ Wv, const float* __restrict__ Ws,
    const float* __restrict__ bq, const float* __restrict__ bk,
    const float* __restrict__ bv, const float* __restrict__ bs,
    float* __restrict__ q1, float* __restrict__ k1,
    float* __restrict__ v1, float* __restrict__ s1)
{
  const int wv = (blockIdx.x * 256 + threadIdx.x) >> 6;
  const int lane = threadIdx.x & 63;
  if (wv >= NN) return;
  float2 h2 = *(const float2*)&h[(size_t)wv * DD + 2 * lane];
  float pq = h2.x * Wq[2 * lane] + h2.y * Wq[2 * lane + 1];
  float pk = h2.x * Wk[2 * lane] + h2.y * Wk[2 * lane + 1];
  float pv = h2.x * Wv[2 * lane] + h2.y * Wv[2 * lane + 1];
  float ps = h2.x * Ws[2 * lane] + h2.y * Ws[2 * lane + 1];
#pragma unroll
  for (int o = 1; o < 64; o <<= 1) {
    pq += __shfl_xor(pq, o); pk += __shfl_xor(pk, o);
    pv += __shfl_xor(pv, o); ps += __shfl_xor(ps, o);
  }
  if (lane == 0) {
    q1[wv] = pq + bq[0]; k1[wv] = pk + bk[0];
    v1[wv] = pv + bv[0]; s1[wv] = ps + bs[0];
  }
}

// ---------------------------------------------------------------------------
// Output conv attention (d=1, scale=1): one thread per node
// ---------------------------------------------------------------------------
__global__ void out_attn(
    const float* __restrict__ q1, const float* __restrict__ k1,
    const float* __restrict__ v1, const float* __restrict__ s1,
    const int* __restrict__ offs, const int* __restrict__ csrc,
    const float* __restrict__ ca, const float* __restrict__ We,
    float* __restrict__ out)
{
  int n = blockIdx.x * 256 + threadIdx.x;
  if (n >= NN) return;
  const float we = We[0];
  const float q = q1[n];
  const int e0 = offs[n], e1 = offs[n + 1];
  float m = -INFINITY;
  for (int e = e0; e < e1; ++e) {
    float al = q * (k1[csrc[e]] + ca[e] * we);
    m = fmaxf(m, al);
  }
  float l = 0.f, acc = 0.f;
  for (int e = e0; e < e1; ++e) {
    int s = csrc[e];
    float al = q * (k1[s] + ca[e] * we);
    float ex = __expf(al - m);
    l += ex;
    acc += ex * (v1[s] + ca[e] * we);
  }
  out[n] = acc / (l + 1e-16f) + s1[n];
}

// ---------------------------------------------------------------------------
extern "C" void kernel_launch(void* const* d_in, const int* in_sizes, int n_in,
                              void* d_out, int out_size, void* d_ws, size_t ws_size,
                              hipStream_t stream)
{
  const float* x_seq = (const float*)d_in[0];
  const int*   ei    = (const int*)  d_in[1];
  const float* ea    = (const float*)d_in[2];
  const float* W_ih  = (const float*)d_in[3];
  const float* W_hh  = (const float*)d_in[4];
  const float* b_ih  = (const float*)d_in[5];
  const float* b_hh  = (const float*)d_in[6];
  const float* cWq   = (const float*)d_in[7];
  const float* cbq   = (const float*)d_in[8];
  const float* cWk   = (const float*)d_in[9];
  const float* cbk   = (const float*)d_in[10];
  const float* cWv   = (const float*)d_in[11];
  const float* cbv   = (const float*)d_in[12];
  const float* cWe   = (const float*)d_in[13];
  const float* cWs   = (const float*)d_in[14];
  const float* cbs   = (const float*)d_in[15];
  const float* oWq   = (const float*)d_in[16];
  const float* obq   = (const float*)d_in[17];
  const float* oWk   = (const float*)d_in[18];
  const float* obk   = (const float*)d_in[19];
  const float* oWv   = (const float*)d_in[20];
  const float* obv   = (const float*)d_in[21];
  const float* oWe   = (const float*)d_in[22];
  const float* oWs   = (const float*)d_in[23];
  const float* obs   = (const float*)d_in[24];
  float* out = (float*)d_out;

  char* ws = (char*)d_ws;
  size_t off = 0;
  auto alloc = [&](size_t bytes) -> char* {
    char* p = ws + off;
    off += (bytes + 255) & ~(size_t)255;
    return p;
  };
  float* fBih  = (float*)alloc((size_t)IND * G3 * 4);
  float* fBhh  = (float*)alloc((size_t)DD * G3 * 4);
  float* fWcat = (float*)alloc((size_t)2 * DD * QS * 4);
  float* fbcat = (float*)alloc((size_t)2 * QS * 4);
  float* fH    = (float*)alloc((size_t)NN * DD * 4);          // GRU h, later h_mean
  float* fHall = (float*)alloc((size_t)T_STEPS * NN * DD * 4);
  int*   iDeg  = (int*)  alloc((size_t)T_STEPS * NN * 4);
  int*   iCur  = (int*)  alloc((size_t)T_STEPS * NN * 4);
  int*   iOffs = (int*)  alloc((size_t)T_STEPS * (NN + 1) * 4);
  int*   iSrc  = (int*)  alloc((size_t)T_STEPS * EE * 4);
  float* fCa   = (float*)alloc((size_t)T_STEPS * EE * 4);
  float* fQ1   = (float*)alloc((size_t)NN * 4);
  float* fK1   = (float*)alloc((size_t)NN * 4);
  float* fV1   = (float*)alloc((size_t)NN * 4);
  float* fS1   = (float*)alloc((size_t)NN * 4);
  // union region: GRU phase uses gi+gh (2x30.72MB); conv phase uses qkvs (40.96MB)
  size_t uniOff = off;
  float* fGi   = (float*)(ws + uniOff);
  float* fGh   = (float*)(ws + uniOff + (size_t)NN * G3 * 4);
  float* fQkvs = (float*)(ws + uniOff);
  (void)ws_size; (void)in_sizes; (void)n_in; (void)out_size;

  auto gemm = [&](const float* A, const float* B, const float* bias, float* C,
                  int M, int N, int K) {
    dim3 g(N / BN, (M + BM - 1) / BM);
    gemm_f32<<<g, 256, 0, stream>>>(A, B, bias, C, M, N, K);
  };

  // weights + CSR + init
  pack_weights<<<(IND*G3 + DD*G3 + 2*DD*QS + 2*QS + 255) / 256, 256, 0, stream>>>(
      W_ih, W_hh, cWq, cWk, cWv, cWs, cbq, cbk, cbv, cbs, fBih, fBhh, fWcat, fbcat);
  hipMemsetAsync(fH, 0, (size_t)NN * DD * 4, stream);
  hipMemsetAsync(iDeg, 0, (size_t)T_STEPS * NN * 4, stream);
  csr_count<<<(T_STEPS * EE + 255) / 256, 256, 0, stream>>>(ei, iDeg);
  csr_scan<<<T_STEPS, 256, 0, stream>>>(iDeg, iOffs, iCur);
  csr_fill<<<(T_STEPS * EE + 255) / 256, 256, 0, stream>>>(ei, ea, iCur, iSrc, fCa);

  // GRU over time
  for (int t = 0; t < T_STEPS; ++t) {
    gemm(x_seq + (size_t)t * NN * IND, fBih, b_ih, fGi, NN, G3, IND);
    gemm(fH, fBhh, b_hh, fGh, NN, G3, DD);
    gru_gate<<<(NN * DD) / 256, 256, 0, stream>>>(fGi, fGh, fH, fHall + (size_t)t * NN * DD);
  }

  // stacked TransformerConv layers
  for (int l = 0; l < 2; ++l) {
    for (int t = 0; t < T_STEPS; ++t) {
      gemm(fHall + (size_t)t * NN * DD, fWcat + (size_t)l * DD * QS,
           fbcat + (size_t)l * QS, fQkvs, NN, QS, DD);
      attn_conv<<<(NN * 64) / 256, 256, 0, stream>>>(
          fQkvs, iOffs + t * (NN + 1), iSrc + (size_t)t * EE, fCa + (size_t)t * EE,
          cWe + l * DD, fHall + (size_t)t * NN * DD);
    }
  }

  // mean over T
  mean_k<<<(NN * DD) / 256, 256, 0, stream>>>(fHall, fH);

  // output conv (d=1) on t=3 graph
  out_proj<<<(NN * 64) / 256, 256, 0, stream>>>(
      fH, oWq, oWk, oWv, oWs, obq, obk, obv, obs, fQ1, fK1, fV1, fS1);
  out_attn<<<(NN + 255) / 256, 256, 0, stream>>>(
      fQ1, fK1, fV1, fS1, iOffs + 3 * (NN + 1), iSrc + (size_t)3 * EE,
      fCa + (size_t)3 * EE, oWe, out);
}

// Round 2
// 926.438 us; speedup vs baseline: 1.6635x; 1.6635x over previous
//
#include <hip/hip_runtime.h>
#include <math.h>

#define T_STEPS 4
#define NN 20000
#define EE 160000
#define IND 64
#define DD 128
#define G3 384     // 3*D (GRU gates)
#define QS 512     // q|k|v|skip fused width

typedef __bf16 bf16x8 __attribute__((ext_vector_type(8)));
typedef float floatx4 __attribute__((ext_vector_type(4)));

// ---------------------------------------------------------------------------
// fp32 -> bf16 split (RNE): x ~= hi + lo, |x-(hi+lo)| <~ 2^-18 |x|
// ---------------------------------------------------------------------------
__device__ inline unsigned short f2bf(float x) {
  unsigned u = __float_as_uint(x);
  unsigned r = (u + 0x7fffu + ((u >> 16) & 1u)) >> 16;
  return (unsigned short)r;
}
__device__ inline float bf2f(unsigned short h) {
  return __uint_as_float((unsigned)h << 16);
}
__device__ inline void bfsplit(float x, unsigned short& hi, unsigned short& lo) {
  hi = f2bf(x);
  lo = f2bf(x - bf2f(hi));
}

// ---------------------------------------------------------------------------
// Split-bf16 MFMA GEMM: C[M,N] = (Ahi+Alo)[M,K] x B + bias, fp32-accurate-ish.
// A: row-major bf16 [M][K] (hi,lo separate). B packed in fragment order:
//   Bp[((n_tile*ktiles + k_tile)*2 + part)*512 + lane*8 + j]
//   holding B[k = k_tile*32 + (lane>>4)*8 + j][n = n_tile*16 + (lane&15)]
// Wave computes 16 rows x 128 cols. Requires M%16==0, N%128==0, K%32==0.
// ---------------------------------------------------------------------------
__global__ __launch_bounds__(256) void gemm_mfma(
    const unsigned short* __restrict__ Ahi, const unsigned short* __restrict__ Alo,
    const unsigned short* __restrict__ Bp, const float* __restrict__ bias,
    float* __restrict__ C, int M, int N, int K)
{
  const int wave = (blockIdx.x * 256 + threadIdx.x) >> 6;
  const int lane = threadIdx.x & 63;
  const int ngroups = N >> 7;          // N/128
  const int mtiles = M >> 4;
  if (wave >= mtiles * ngroups) return;
  const int mw = wave / ngroups;
  const int ng = wave - mw * ngroups;
  const int r = lane & 15, quad = lane >> 4;
  const int ktiles = K >> 5;
  const int row = mw * 16 + r;
  const unsigned short* arh = Ahi + (size_t)row * K + quad * 8;
  const unsigned short* arl = Alo + (size_t)row * K + quad * 8;
  floatx4 acc[8];
#pragma unroll
  for (int nt = 0; nt < 8; ++nt) acc[nt] = (floatx4){0.f, 0.f, 0.f, 0.f};
  const int n0t = ng * 8;
  for (int kt = 0; kt < ktiles; ++kt) {
    bf16x8 ahi = *(const bf16x8*)(arh + kt * 32);
    bf16x8 alo = *(const bf16x8*)(arl + kt * 32);
#pragma unroll
    for (int nt = 0; nt < 8; ++nt) {
      const unsigned short* bp =
          Bp + ((size_t)((n0t + nt) * ktiles + kt)) * 1024 + lane * 8;
      bf16x8 bhi = *(const bf16x8*)bp;
      bf16x8 blo = *(const bf16x8*)(bp + 512);
      acc[nt] = __builtin_amdgcn_mfma_f32_16x16x32_bf16(ahi, bhi, acc[nt], 0, 0, 0);
      acc[nt] = __builtin_amdgcn_mfma_f32_16x16x32_bf16(ahi, blo, acc[nt], 0, 0, 0);
      acc[nt] = __builtin_amdgcn_mfma_f32_16x16x32_bf16(alo, bhi, acc[nt], 0, 0, 0);
    }
  }
  // C/D layout: col = lane&15, row = quad*4 + reg
  const int crow0 = mw * 16 + quad * 4;
#pragma unroll
  for (int nt = 0; nt < 8; ++nt) {
    const int col = ng * 128 + nt * 16 + r;
    const float b = bias[col];
#pragma unroll
    for (int i = 0; i < 4; ++i)
      C[(size_t)(crow0 + i) * N + col] = acc[nt][i] + b;
  }
}

// ---------------------------------------------------------------------------
// Weight packing into MFMA fragment order (hi/lo split) + fused conv bias
// ---------------------------------------------------------------------------
#define BIH_PAIRS 24576    // (384/16)*(64/32)*512
#define BHH_PAIRS 49152    // 24*4*512
#define WCAT_PAIRS 131072  // 2*32*4*512
#define BCAT_N 1024

__global__ void pack_weights(
    const float* __restrict__ Wih, const float* __restrict__ Whh,
    const float* __restrict__ Wq, const float* __restrict__ Wk,
    const float* __restrict__ Wv, const float* __restrict__ Ws,
    const float* __restrict__ bq, const float* __restrict__ bk,
    const float* __restrict__ bv, const float* __restrict__ bs,
    unsigned short* __restrict__ BihP, unsigned short* __restrict__ BhhP,
    unsigned short* __restrict__ WcatP, float* __restrict__ bcat)
{
  int gid = blockIdx.x * 256 + threadIdx.x;
  if (gid < BIH_PAIRS) {  // K=64, N=384, ktiles=2
    int tile = gid >> 9, lj = gid & 511, lane = lj >> 3, j = lj & 7;
    int k_tile = tile & 1, n_tile = tile >> 1;
    int n = n_tile * 16 + (lane & 15);
    int k = k_tile * 32 + (lane >> 4) * 8 + j;
    unsigned short hi, lo;
    bfsplit(Wih[n * IND + k], hi, lo);   // B[k][n] = Wih^T
    BihP[tile * 1024 + lane * 8 + j] = hi;
    BihP[tile * 1024 + 512 + lane * 8 + j] = lo;
    return;
  }
  gid -= BIH_PAIRS;
  if (gid < BHH_PAIRS) {  // K=128, N=384, ktiles=4
    int tile = gid >> 9, lj = gid & 511, lane = lj >> 3, j = lj & 7;
    int k_tile = tile & 3, n_tile = tile >> 2;
    int n = n_tile * 16 + (lane & 15);
    int k = k_tile * 32 + (lane >> 4) * 8 + j;
    unsigned short hi, lo;
    bfsplit(Whh[n * DD + k], hi, lo);
    BhhP[tile * 1024 + lane * 8 + j] = hi;
    BhhP[tile * 1024 + 512 + lane * 8 + j] = lo;
    return;
  }
  gid -= BHH_PAIRS;
  if (gid < WCAT_PAIRS) {  // per layer: K=128, N=512, ktiles=4
    int l = gid >> 16, rem = gid & 65535;
    int tile = rem >> 9, lj = rem & 511, lane = lj >> 3, j = lj & 7;
    int k_tile = tile & 3, n_tile = tile >> 2;
    int n = n_tile * 16 + (lane & 15);
    int k = k_tile * 32 + (lane >> 4) * 8 + j;
    const float* W = (n < 128) ? Wq : (n < 256) ? Wk : (n < 384) ? Wv : Ws;
    unsigned short hi, lo;
    bfsplit(W[l * DD * DD + k * DD + (n & 127)], hi, lo);
    size_t base = (size_t)l * 131072 + tile * 1024;
    WcatP[base + lane * 8 + j] = hi;
    WcatP[base + 512 + lane * 8 + j] = lo;
    return;
  }
  gid -= WCAT_PAIRS;
  if (gid < BCAT_N) {
    int l = gid >> 9, n = gid & 511;
    const float* b = (n < 128) ? bq : (n < 256) ? bk : (n < 384) ? bv : bs;
    bcat[gid] = b[l * DD + (n & 127)];
  }
}

// ---------------------------------------------------------------------------
// x_seq -> bf16 hi/lo split
// ---------------------------------------------------------------------------
__global__ void xsplit(const float* __restrict__ x,
                       unsigned short* __restrict__ xhi,
                       unsigned short* __restrict__ xlo)
{
  int i = blockIdx.x * 256 + threadIdx.x;   // exact T*NN*IND grid
  unsigned short hi, lo;
  bfsplit(x[i], hi, lo);
  xhi[i] = hi; xlo[i] = lo;
}

// ---------------------------------------------------------------------------
// CSR build (by destination), per timestep; parallel 3-phase scan
// ---------------------------------------------------------------------------
#define SCHUNK 1024
#define NCHUNK 20          // ceil(20000/1024)

__global__ void csr_count(const int* __restrict__ ei, int* __restrict__ deg)
{
  int gid = blockIdx.x * 256 + threadIdx.x;
  if (gid >= T_STEPS * EE) return;
  int t = gid / EE, e = gid % EE;
  int dst = ei[(size_t)t * 2 * EE + EE + e];
  atomicAdd(&deg[t * NN + dst], 1);
}

__global__ void scan1(const int* __restrict__ deg, int* __restrict__ part)
{
  const int b = blockIdx.x;              // 0..T*NCHUNK-1
  const int t = b / NCHUNK, c = b % NCHUNK;
  const int tid = threadIdx.x;
  __shared__ int s[256];
  int base = c * SCHUNK + tid * 4;
  int sum = 0;
#pragma unroll
  for (int u = 0; u < 4; ++u) {
    int i = base + u;
    if (i < NN) sum += deg[t * NN + i];
  }
  s[tid] = sum;
  __syncthreads();
  for (int o = 128; o > 0; o >>= 1) {
    if (tid < o) s[tid] += s[tid + o];
    __syncthreads();
  }
  if (tid == 0) part[b] = s[0];
}

__global__ void scan2(int* __restrict__ part, int* __restrict__ offs)
{
  const int tid = threadIdx.x;
  __shared__ int s[T_STEPS * NCHUNK];
  if (tid < T_STEPS * NCHUNK) s[tid] = part[tid];
  __syncthreads();
  if (tid == 0) {
    for (int t = 0; t < T_STEPS; ++t) {
      int run = 0;
      for (int c = 0; c < NCHUNK; ++c) {
        int v = s[t * NCHUNK + c];
        s[t * NCHUNK + c] = run;
        run += v;
      }
      offs[t * (NN + 1) + NN] = run;
    }
  }
  __syncthreads();
  if (tid < T_STEPS * NCHUNK) part[tid] = s[tid];
}

__global__ void scan3(const int* __restrict__ deg, const int* __restrict__ part,
                      int* __restrict__ offs, int* __restrict__ cur)
{
  const int b = blockIdx.x;
  const int t = b / NCHUNK, c = b % NCHUNK;
  const int tid = threadIdx.x;
  __shared__ int s[256];
  int base = c * SCHUNK + tid * 4;
  int v[4]; int sum = 0;
#pragma unroll
  for (int u = 0; u < 4; ++u) {
    int i = base + u;
    v[u] = (i < NN) ? deg[t * NN + i] : 0;
    sum += v[u];
  }
  s[tid] = sum;
  __syncthreads();
  for (int o = 1; o < 256; o <<= 1) {
    int x = (tid >= o) ? s[tid - o] : 0;
    __syncthreads();
    s[tid] += x;
    __syncthreads();
  }
  int excl = part[b] + s[tid] - sum;
#pragma unroll
  for (int u = 0; u < 4; ++u) {
    int i = base + u;
    if (i < NN) {
      offs[t * (NN + 1) + i] = excl;
      cur[t * NN + i] = excl;
    }
    excl += v[u];
  }
}

__global__ void csr_fill(const int* __restrict__ ei, const float* __restrict__ ea,
                         int* __restrict__ cur, int* __restrict__ csrc,
                         float* __restrict__ ca)
{
  int gid = blockIdx.x * 256 + threadIdx.x;
  if (gid >= T_STEPS * EE) return;
  int t = gid / EE, e = gid % EE;
  int src = ei[(size_t)t * 2 * EE + e];
  int dst = ei[(size_t)t * 2 * EE + EE + e];
  int slot = atomicAdd(&cur[t * NN + dst], 1);
  csrc[t * EE + slot] = src;
  ca[t * EE + slot] = ea[(size_t)t * EE + e];
}

// ---------------------------------------------------------------------------
// GRU gate fusion; writes h (fp32, recurrence) + hi/lo bf16 for next GEMMs
// ---------------------------------------------------------------------------
__global__ __launch_bounds__(256) void gru_gate(
    const float* __restrict__ gi, const float* __restrict__ gh,
    float* __restrict__ h,
    unsigned short* __restrict__ hhi_t, unsigned short* __restrict__ hlo_t)
{
  int idx = blockIdx.x * 256 + threadIdx.x;   // exact NN*DD grid
  int n = idx >> 7, d = idx & 127;
  size_t gb = (size_t)n * G3 + d;
  float ir = gi[gb], iz = gi[gb + DD], inn = gi[gb + 2 * DD];
  float hr = gh[gb], hz = gh[gb + DD], hn = gh[gb + 2 * DD];
  float r = 1.f / (1.f + __expf(-(ir + hr)));
  float z = 1.f / (1.f + __expf(-(iz + hz)));
  float nv = tanhf(inn + r * hn);
  float hp = h[idx];
  float hnew = (1.f - z) * nv + z * hp;
  h[idx] = hnew;
  unsigned short hi, lo;
  bfsplit(hnew, hi, lo);
  hhi_t[idx] = hi; hlo_t[idx] = lo;
}

// ---------------------------------------------------------------------------
// Fused TransformerConv (d=128): one wave per dst node, online softmax.
// Writes fp32 (for mean) + bf16 hi/lo (next layer's GEMM input).
// ---------------------------------------------------------------------------
__global__ __launch_bounds__(256) void attn_conv(
    const float* __restrict__ qkvs,   // [NN,512]
    const int* __restrict__ offs, const int* __restrict__ csrc,
    const float* __restrict__ ca, const float* __restrict__ We,
    float* __restrict__ hout,
    unsigned short* __restrict__ hhi, unsigned short* __restrict__ hlo)
{
  const int wv = (blockIdx.x * 256 + threadIdx.x) >> 6;
  const int lane = threadIdx.x & 63;
  if (wv >= NN) return;
  const float scale = 0.08838834764831845f;   // 1/sqrt(128)
  const float2 q  = *(const float2*)&qkvs[(size_t)wv * QS + 2 * lane];
  const float2 w2 = *(const float2*)&We[2 * lane];
  float qwe = q.x * w2.x + q.y * w2.y;
#pragma unroll
  for (int o = 1; o < 64; o <<= 1) qwe += __shfl_xor(qwe, o);
  const int e0 = offs[wv], e1 = offs[wv + 1];
  float m_run = -INFINITY, l_run = 0.f;
  float accx = 0.f, accy = 0.f;
  for (int base = e0; base < e1; base += 64) {
    const int cnt = min(64, e1 - base);
    int msrc = 0; float ma = 0.f;
    if (lane < cnt) { msrc = csrc[base + lane]; ma = ca[base + lane]; }
    float malpha = -INFINITY;
    for (int j = 0; j < cnt; ++j) {
      const int s = __shfl(msrc, j);
      const float a = __shfl(ma, j);
      const float2 k2 = *(const float2*)&qkvs[(size_t)s * QS + 128 + 2 * lane];
      float p = q.x * k2.x + q.y * k2.y;
#pragma unroll
      for (int o = 1; o < 64; o <<= 1) p += __shfl_xor(p, o);
      const float alpha = (p + a * qwe) * scale;
      if (lane == j) malpha = alpha;
    }
    float cm = malpha;
#pragma unroll
    for (int o = 1; o < 64; o <<= 1) cm = fmaxf(cm, __shfl_xor(cm, o));
    const float m_new = fmaxf(m_run, cm);
    const float fac = __expf(m_run - m_new);
    const float ex = (lane < cnt) ? __expf(malpha - m_new) : 0.f;
    float sx = ex;
#pragma unroll
    for (int o = 1; o < 64; o <<= 1) sx += __shfl_xor(sx, o);
    l_run = l_run * fac + sx;
    accx *= fac; accy *= fac;
    for (int j = 0; j < cnt; ++j) {
      const int s = __shfl(msrc, j);
      const float a = __shfl(ma, j);
      const float w = __shfl(ex, j);
      const float2 v2 = *(const float2*)&qkvs[(size_t)s * QS + 256 + 2 * lane];
      accx += w * (v2.x + a * w2.x);
      accy += w * (v2.y + a * w2.y);
    }
    m_run = m_new;
  }
  const float inv = 1.f / (l_run + 1e-16f);
  const float2 sk = *(const float2*)&qkvs[(size_t)wv * QS + 384 + 2 * lane];
  float ox = accx * inv + sk.x;
  float oy = accy * inv + sk.y;
  ox = (ox > 0.f) ? ox : 0.01f * ox;
  oy = (oy > 0.f) ? oy : 0.01f * oy;
  *(float2*)&hout[(size_t)wv * DD + 2 * lane] = make_float2(ox, oy);
  unsigned short hx, lx, hy, ly;
  bfsplit(ox, hx, lx); bfsplit(oy, hy, ly);
  *(unsigned int*)&hhi[(size_t)wv * DD + 2 * lane] = ((unsigned)hy << 16) | hx;
  *(unsigned int*)&hlo[(size_t)wv * DD + 2 * lane] = ((unsigned)ly << 16) | lx;
}

// ---------------------------------------------------------------------------
__global__ void mean_k(const float* __restrict__ hall, float* __restrict__ hm)
{
  int i = blockIdx.x * 256 + threadIdx.x;
  float v = hall[i] + hall[i + NN * DD] + hall[i + 2 * NN * DD] + hall[i + 3 * NN * DD];
  hm[i] = 0.25f * v;
}

__global__ __launch_bounds__(256) void out_proj(
    const float* __restrict__ h,
    const float* __restrict__ Wq, const float* __restrict__ Wk,
    const float* __restrict__ Wv, const float* __restrict__ Ws,
    const float* __restrict__ bq, const float* __restrict__ bk,
    const float* __restrict__ bv, const float* __restrict__ bs,
    float* __restrict__ q1, float* __restrict__ k1,
    float* __restrict__ v1, float* __restrict__ s1)
{
  const int wv = (blockIdx.x * 256 + threadIdx.x) >> 6;
  const int lane = threadIdx.x & 63;
  if (wv >= NN) return;
  float2 h2 = *(const float2*)&h[(size_t)wv * DD + 2 * lane];
  float pq = h2.x * Wq[2 * lane] + h2.y * Wq[2 * lane + 1];
  float pk = h2.x * Wk[2 * lane] + h2.y * Wk[2 * lane + 1];
  float pv = h2.x * Wv[2 * lane] + h2.y * Wv[2 * lane + 1];
  float ps = h2.x * Ws[2 * lane] + h2.y * Ws[2 * lane + 1];
#pragma unroll
  for (int o = 1; o < 64; o <<= 1) {
    pq += __shfl_xor(pq, o); pk += __shfl_xor(pk, o);
    pv += __shfl_xor(pv, o); ps += __shfl_xor(ps, o);
  }
  if (lane == 0) {
    q1[wv] = pq + bq[0]; k1[wv] = pk + bk[0];
    v1[wv] = pv + bv[0]; s1[wv] = ps + bs[0];
  }
}

__global__ void out_attn(
    const float* __restrict__ q1, const float* __restrict__ k1,
    const float* __restrict__ v1, const float* __restrict__ s1,
    const int* __restrict__ offs, const int* __restrict__ csrc,
    const float* __restrict__ ca, const float* __restrict__ We,
    float* __restrict__ out)
{
  int n = blockIdx.x * 256 + threadIdx.x;
  if (n >= NN) return;
  const float we = We[0];
  const float q = q1[n];
  const int e0 = offs[n], e1 = offs[n + 1];
  float m = -INFINITY;
  for (int e = e0; e < e1; ++e) {
    float al = q * (k1[csrc[e]] + ca[e] * we);
    m = fmaxf(m, al);
  }
  float l = 0.f, acc = 0.f;
  for (int e = e0; e < e1; ++e) {
    int s = csrc[e];
    float al = q * (k1[s] + ca[e] * we);
    float ex = __expf(al - m);
    l += ex;
    acc += ex * (v1[s] + ca[e] * we);
  }
  out[n] = acc / (l + 1e-16f) + s1[n];
}

// ---------------------------------------------------------------------------
extern "C" void kernel_launch(void* const* d_in, const int* in_sizes, int n_in,
                              void* d_out, int out_size, void* d_ws, size_t ws_size,
                              hipStream_t stream)
{
  const float* x_seq = (const float*)d_in[0];
  const int*   ei    = (const int*)  d_in[1];
  const float* ea    = (const float*)d_in[2];
  const float* W_ih  = (const float*)d_in[3];
  const float* W_hh  = (const float*)d_in[4];
  const float* b_ih  = (const float*)d_in[5];
  const float* b_hh  = (const float*)d_in[6];
  const float* cWq   = (const float*)d_in[7];
  const float* cbq   = (const float*)d_in[8];
  const float* cWk   = (const float*)d_in[9];
  const float* cbk   = (const float*)d_in[10];
  const float* cWv   = (const float*)d_in[11];
  const float* cbv   = (const float*)d_in[12];
  const float* cWe   = (const float*)d_in[13];
  const float* cWs   = (const float*)d_in[14];
  const float* cbs   = (const float*)d_in[15];
  const float* oWq   = (const float*)d_in[16];
  const float* obq   = (const float*)d_in[17];
  const float* oWk   = (const float*)d_in[18];
  const float* obk   = (const float*)d_in[19];
  const float* oWv   = (const float*)d_in[20];
  const float* obv   = (const float*)d_in[21];
  const float* oWe   = (const float*)d_in[22];
  const float* oWs   = (const float*)d_in[23];
  const float* obs   = (const float*)d_in[24];
  float* out = (float*)d_out;

  char* ws = (char*)d_ws;
  size_t off = 0;
  auto alloc = [&](size_t bytes) -> char* {
    char* p = ws + off;
    off += (bytes + 255) & ~(size_t)255;
    return p;
  };
  unsigned short* BihP  = (unsigned short*)alloc((size_t)2 * BIH_PAIRS * 2);
  unsigned short* BhhP  = (unsigned short*)alloc((size_t)2 * BHH_PAIRS * 2);
  unsigned short* WcatP = (unsigned short*)alloc((size_t)2 * WCAT_PAIRS * 2);
  float* fbcat = (float*)alloc((size_t)BCAT_N * 4);
  unsigned short* xhi   = (unsigned short*)alloc((size_t)T_STEPS * NN * IND * 2);
  unsigned short* xlo   = (unsigned short*)alloc((size_t)T_STEPS * NN * IND * 2);
  unsigned short* hallhi = (unsigned short*)alloc((size_t)T_STEPS * NN * DD * 2);
  unsigned short* halllo = (unsigned short*)alloc((size_t)T_STEPS * NN * DD * 2);
  unsigned short* fZ    = (unsigned short*)alloc((size_t)NN * DD * 2);
  float* fH    = (float*)alloc((size_t)NN * DD * 4);          // GRU h, later h_mean
  float* fHall = (float*)alloc((size_t)T_STEPS * NN * DD * 4);
  int*   iDeg  = (int*)  alloc((size_t)T_STEPS * NN * 4);
  int*   iCur  = (int*)  alloc((size_t)T_STEPS * NN * 4);
  int*   iOffs = (int*)  alloc((size_t)T_STEPS * (NN + 1) * 4);
  int*   iPart = (int*)  alloc((size_t)T_STEPS * NCHUNK * 4);
  int*   iSrc  = (int*)  alloc((size_t)T_STEPS * EE * 4);
  float* fCa   = (float*)alloc((size_t)T_STEPS * EE * 4);
  float* fQ1   = (float*)alloc((size_t)NN * 4);
  float* fK1   = (float*)alloc((size_t)NN * 4);
  float* fV1   = (float*)alloc((size_t)NN * 4);
  float* fS1   = (float*)alloc((size_t)NN * 4);
  // union region: GRU phase uses gi+gh; conv phase uses qkvs
  size_t uniOff = off;
  float* fGi   = (float*)(ws + uniOff);
  float* fGh   = (float*)(ws + uniOff + (size_t)NN * G3 * 4);
  float* fQkvs = (float*)(ws + uniOff);
  (void)ws_size; (void)in_sizes; (void)n_in; (void)out_size;

  auto gemm = [&](const unsigned short* Ahi, const unsigned short* Alo,
                  const unsigned short* Bp, const float* bias, float* C,
                  int M, int N, int K) {
    int waves = (M >> 4) * (N >> 7);
    gemm_mfma<<<(waves + 3) / 4, 256, 0, stream>>>(Ahi, Alo, Bp, bias, C, M, N, K);
  };

  // weights + activation split + CSR + init
  pack_weights<<<(BIH_PAIRS + BHH_PAIRS + WCAT_PAIRS + BCAT_N + 255) / 256, 256, 0,
                 stream>>>(W_ih, W_hh, cWq, cWk, cWv, cWs, cbq, cbk, cbv, cbs,
                           BihP, BhhP, WcatP, fbcat);
  xsplit<<<(T_STEPS * NN * IND) / 256, 256, 0, stream>>>(x_seq, xhi, xlo);
  hipMemsetAsync(fH, 0, (size_t)NN * DD * 4, stream);
  hipMemsetAsync(fZ, 0, (size_t)NN * DD * 2, stream);
  hipMemsetAsync(iDeg, 0, (size_t)T_STEPS * NN * 4, stream);
  csr_count<<<(T_STEPS * EE + 255) / 256, 256, 0, stream>>>(ei, iDeg);
  scan1<<<T_STEPS * NCHUNK, 256, 0, stream>>>(iDeg, iPart);
  scan2<<<1, 128, 0, stream>>>(iPart, iOffs);
  scan3<<<T_STEPS * NCHUNK, 256, 0, stream>>>(iDeg, iPart, iOffs, iCur);
  csr_fill<<<(T_STEPS * EE + 255) / 256, 256, 0, stream>>>(ei, ea, iCur, iSrc, fCa);

  // GRU over time
  for (int t = 0; t < T_STEPS; ++t) {
    gemm(xhi + (size_t)t * NN * IND, xlo + (size_t)t * NN * IND, BihP, b_ih,
         fGi, NN, G3, IND);
    const unsigned short* phi = (t == 0) ? fZ : hallhi + (size_t)(t - 1) * NN * DD;
    const unsigned short* plo = (t == 0) ? fZ : halllo + (size_t)(t - 1) * NN * DD;
    gemm(phi, plo, BhhP, b_hh, fGh, NN, G3, DD);
    gru_gate<<<(NN * DD) / 256, 256, 0, stream>>>(
        fGi, fGh, fH, hallhi + (size_t)t * NN * DD, halllo + (size_t)t * NN * DD);
  }

  // stacked TransformerConv layers (read hi/lo of layer input, write back)
  for (int l = 0; l < 2; ++l) {
    for (int t = 0; t < T_STEPS; ++t) {
      gemm(hallhi + (size_t)t * NN * DD, halllo + (size_t)t * NN * DD,
           WcatP + (size_t)l * 131072, fbcat + (size_t)l * QS, fQkvs, NN, QS, DD);
      attn_conv<<<(NN * 64) / 256, 256, 0, stream>>>(
          fQkvs, iOffs + t * (NN + 1), iSrc + (size_t)t * EE, fCa + (size_t)t * EE,
          cWe + l * DD, fHall + (size_t)t * NN * DD,
          hallhi + (size_t)t * NN * DD, halllo + (size_t)t * NN * DD);
    }
  }

  // mean over T
  mean_k<<<(NN * DD) / 256, 256, 0, stream>>>(fHall, fH);

  // output conv (d=1) on t=3 graph
  out_proj<<<(NN * 64) / 256, 256, 0, stream>>>(
      fH, oWq, oWk, oWv, oWs, obq, obk, obv, obs, fQ1, fK1, fV1, fS1);
  out_attn<<<(NN + 255) / 256, 256, 0, stream>>>(
      fQ1, fK1, fV1, fS1, iOffs + 3 * (NN + 1), iSrc + (size_t)3 * EE,
      fCa + (size_t)3 * EE, oWe, out);
}

// Round 4
// 738.573 us; speedup vs baseline: 2.0867x; 1.2544x over previous
//
#include <hip/hip_runtime.h>
#include <math.h>

#define T_STEPS 4
#define NN 20000
#define EE 160000
#define IND 64
#define DD 128
#define G3 384     // 3*D (GRU gates)
#define QS 512     // q|k|v|skip fused width

typedef __bf16 bf16x8 __attribute__((ext_vector_type(8)));
typedef float floatx4 __attribute__((ext_vector_type(4)));

// ---------------------------------------------------------------------------
// fp32 -> bf16 split (RNE): x ~= hi + lo, |x-(hi+lo)| <~ 2^-18 |x|
// ---------------------------------------------------------------------------
__device__ inline unsigned short f2bf(float x) {
  unsigned u = __float_as_uint(x);
  unsigned r = (u + 0x7fffu + ((u >> 16) & 1u)) >> 16;
  return (unsigned short)r;
}
__device__ inline float bf2f(unsigned short h) {
  return __uint_as_float((unsigned)h << 16);
}
__device__ inline void bfsplit(float x, unsigned short& hi, unsigned short& lo) {
  hi = f2bf(x);
  lo = f2bf(x - bf2f(hi));
}

// ---------------------------------------------------------------------------
// Split-bf16 MFMA GEMM: C[M,N] = (Ahi+Alo)[M,K] x B + bias.
// Wave computes 32 rows x 128 cols. Requires M%32==0, N%128==0, K%32==0.
// ---------------------------------------------------------------------------
__global__ __launch_bounds__(256) void gemm_mfma(
    const unsigned short* __restrict__ Ahi, const unsigned short* __restrict__ Alo,
    const unsigned short* __restrict__ Bp, const float* __restrict__ bias,
    float* __restrict__ C, int M, int N, int K)
{
  const int wave = (blockIdx.x * 256 + threadIdx.x) >> 6;
  const int lane = threadIdx.x & 63;
  const int ngroups = N >> 7;          // N/128
  const int mtiles = M >> 5;           // 32 rows per wave
  if (wave >= mtiles * ngroups) return;
  const int mw = wave / ngroups;
  const int ng = wave - mw * ngroups;
  const int r = lane & 15, quad = lane >> 4;
  const int ktiles = K >> 5;
  const unsigned short* a0h = Ahi + (size_t)(mw * 32 + r) * K + quad * 8;
  const unsigned short* a0l = Alo + (size_t)(mw * 32 + r) * K + quad * 8;
  const unsigned short* a1h = a0h + (size_t)16 * K;
  const unsigned short* a1l = a0l + (size_t)16 * K;
  floatx4 acc[2][8];
#pragma unroll
  for (int m = 0; m < 2; ++m)
#pragma unroll
    for (int nt = 0; nt < 8; ++nt) acc[m][nt] = (floatx4){0.f, 0.f, 0.f, 0.f};
  const int n0t = ng * 8;
  for (int kt = 0; kt < ktiles; ++kt) {
    bf16x8 a0hi = *(const bf16x8*)(a0h + kt * 32);
    bf16x8 a0lo = *(const bf16x8*)(a0l + kt * 32);
    bf16x8 a1hi = *(const bf16x8*)(a1h + kt * 32);
    bf16x8 a1lo = *(const bf16x8*)(a1l + kt * 32);
#pragma unroll
    for (int nt = 0; nt < 8; ++nt) {
      const unsigned short* bp =
          Bp + ((size_t)((n0t + nt) * ktiles + kt)) * 1024 + lane * 8;
      bf16x8 bhi = *(const bf16x8*)bp;
      bf16x8 blo = *(const bf16x8*)(bp + 512);
      acc[0][nt] = __builtin_amdgcn_mfma_f32_16x16x32_bf16(a0hi, bhi, acc[0][nt], 0, 0, 0);
      acc[0][nt] = __builtin_amdgcn_mfma_f32_16x16x32_bf16(a0hi, blo, acc[0][nt], 0, 0, 0);
      acc[0][nt] = __builtin_amdgcn_mfma_f32_16x16x32_bf16(a0lo, bhi, acc[0][nt], 0, 0, 0);
      acc[1][nt] = __builtin_amdgcn_mfma_f32_16x16x32_bf16(a1hi, bhi, acc[1][nt], 0, 0, 0);
      acc[1][nt] = __builtin_amdgcn_mfma_f32_16x16x32_bf16(a1hi, blo, acc[1][nt], 0, 0, 0);
      acc[1][nt] = __builtin_amdgcn_mfma_f32_16x16x32_bf16(a1lo, bhi, acc[1][nt], 0, 0, 0);
    }
  }
#pragma unroll
  for (int m = 0; m < 2; ++m) {
    const int crow0 = mw * 32 + m * 16 + quad * 4;
#pragma unroll
    for (int nt = 0; nt < 8; ++nt) {
      const int col = ng * 128 + nt * 16 + r;
      const float b = bias[col];
#pragma unroll
      for (int i = 0; i < 4; ++i)
        C[(size_t)(crow0 + i) * N + col] = acc[m][nt][i] + b;
    }
  }
}

// ---------------------------------------------------------------------------
// Weight packing into MFMA fragment order (hi/lo split) + fused conv bias
// ---------------------------------------------------------------------------
#define BIH_PAIRS 24576    // (384/16)*(64/32)*512
#define BHH_PAIRS 49152    // 24*4*512
#define WCAT_PAIRS 131072  // 2*32*4*512
#define BCAT_N 1024

__global__ void pack_weights(
    const float* __restrict__ Wih, const float* __restrict__ Whh,
    const float* __restrict__ Wq, const float* __restrict__ Wk,
    const float* __restrict__ Wv, const float* __restrict__ Ws,
    const float* __restrict__ bq, const float* __restrict__ bk,
    const float* __restrict__ bv, const float* __restrict__ bs,
    unsigned short* __restrict__ BihP, unsigned short* __restrict__ BhhP,
    unsigned short* __restrict__ WcatP, float* __restrict__ bcat)
{
  int gid = blockIdx.x * 256 + threadIdx.x;
  if (gid < BIH_PAIRS) {  // K=64, N=384, ktiles=2
    int tile = gid >> 9, lj = gid & 511, lane = lj >> 3, j = lj & 7;
    int k_tile = tile & 1, n_tile = tile >> 1;
    int n = n_tile * 16 + (lane & 15);
    int k = k_tile * 32 + (lane >> 4) * 8 + j;
    unsigned short hi, lo;
    bfsplit(Wih[n * IND + k], hi, lo);   // B[k][n] = Wih^T
    BihP[tile * 1024 + lane * 8 + j] = hi;
    BihP[tile * 1024 + 512 + lane * 8 + j] = lo;
    return;
  }
  gid -= BIH_PAIRS;
  if (gid < BHH_PAIRS) {  // K=128, N=384, ktiles=4
    int tile = gid >> 9, lj = gid & 511, lane = lj >> 3, j = lj & 7;
    int k_tile = tile & 3, n_tile = tile >> 2;
    int n = n_tile * 16 + (lane & 15);
    int k = k_tile * 32 + (lane >> 4) * 8 + j;
    unsigned short hi, lo;
    bfsplit(Whh[n * DD + k], hi, lo);
    BhhP[tile * 1024 + lane * 8 + j] = hi;
    BhhP[tile * 1024 + 512 + lane * 8 + j] = lo;
    return;
  }
  gid -= BHH_PAIRS;
  if (gid < WCAT_PAIRS) {  // per layer: K=128, N=512, ktiles=4
    int l = gid >> 16, rem = gid & 65535;
    int tile = rem >> 9, lj = rem & 511, lane = lj >> 3, j = lj & 7;
    int k_tile = tile & 3, n_tile = tile >> 2;
    int n = n_tile * 16 + (lane & 15);
    int k = k_tile * 32 + (lane >> 4) * 8 + j;
    const float* W = (n < 128) ? Wq : (n < 256) ? Wk : (n < 384) ? Wv : Ws;
    unsigned short hi, lo;
    bfsplit(W[l * DD * DD + k * DD + (n & 127)], hi, lo);
    size_t base = (size_t)l * 131072 + tile * 1024;
    WcatP[base + lane * 8 + j] = hi;
    WcatP[base + 512 + lane * 8 + j] = lo;
    return;
  }
  gid -= WCAT_PAIRS;
  if (gid < BCAT_N) {
    int l = gid >> 9, n = gid & 511;
    const float* b = (n < 128) ? bq : (n < 256) ? bk : (n < 384) ? bv : bs;
    bcat[gid] = b[l * DD + (n & 127)];
  }
}

// ---------------------------------------------------------------------------
__global__ void xsplit(const float* __restrict__ x,
                       unsigned short* __restrict__ xhi,
                       unsigned short* __restrict__ xlo)
{
  int i = blockIdx.x * 256 + threadIdx.x;   // exact T*NN*IND grid
  unsigned short hi, lo;
  bfsplit(x[i], hi, lo);
  xhi[i] = hi; xlo[i] = lo;
}

// ---------------------------------------------------------------------------
// CSR build (by destination), per timestep; parallel 3-phase scan
// ---------------------------------------------------------------------------
#define SCHUNK 1024
#define NCHUNK 20          // ceil(20000/1024)

__global__ void csr_count(const int* __restrict__ ei, int* __restrict__ deg)
{
  int gid = blockIdx.x * 256 + threadIdx.x;
  if (gid >= T_STEPS * EE) return;
  int t = gid / EE, e = gid % EE;
  int dst = ei[(size_t)t * 2 * EE + EE + e];
  atomicAdd(&deg[t * NN + dst], 1);
}

__global__ void scan1(const int* __restrict__ deg, int* __restrict__ part)
{
  const int b = blockIdx.x;              // 0..T*NCHUNK-1
  const int t = b / NCHUNK, c = b % NCHUNK;
  const int tid = threadIdx.x;
  __shared__ int s[256];
  int base = c * SCHUNK + tid * 4;
  int sum = 0;
#pragma unroll
  for (int u = 0; u < 4; ++u) {
    int i = base + u;
    if (i < NN) sum += deg[t * NN + i];
  }
  s[tid] = sum;
  __syncthreads();
  for (int o = 128; o > 0; o >>= 1) {
    if (tid < o) s[tid] += s[tid + o];
    __syncthreads();
  }
  if (tid == 0) part[b] = s[0];
}

__global__ void scan2(int* __restrict__ part, int* __restrict__ offs)
{
  const int tid = threadIdx.x;
  __shared__ int s[T_STEPS * NCHUNK];
  if (tid < T_STEPS * NCHUNK) s[tid] = part[tid];
  __syncthreads();
  if (tid == 0) {
    for (int t = 0; t < T_STEPS; ++t) {
      int run = 0;
      for (int c = 0; c < NCHUNK; ++c) {
        int v = s[t * NCHUNK + c];
        s[t * NCHUNK + c] = run;
        run += v;
      }
      offs[t * (NN + 1) + NN] = run;
    }
  }
  __syncthreads();
  if (tid < T_STEPS * NCHUNK) part[tid] = s[tid];
}

__global__ void scan3(const int* __restrict__ deg, const int* __restrict__ part,
                      int* __restrict__ offs, int* __restrict__ cur)
{
  const int b = blockIdx.x;
  const int t = b / NCHUNK, c = b % NCHUNK;
  const int tid = threadIdx.x;
  __shared__ int s[256];
  int base = c * SCHUNK + tid * 4;
  int v[4]; int sum = 0;
#pragma unroll
  for (int u = 0; u < 4; ++u) {
    int i = base + u;
    v[u] = (i < NN) ? deg[t * NN + i] : 0;
    sum += v[u];
  }
  s[tid] = sum;
  __syncthreads();
  for (int o = 1; o < 256; o <<= 1) {
    int x = (tid >= o) ? s[tid - o] : 0;
    __syncthreads();
    s[tid] += x;
    __syncthreads();
  }
  int excl = part[b] + s[tid] - sum;
#pragma unroll
  for (int u = 0; u < 4; ++u) {
    int i = base + u;
    if (i < NN) {
      offs[t * (NN + 1) + i] = excl;
      cur[t * NN + i] = excl;
    }
    excl += v[u];
  }
}

// packed CSR entry: .x = src node, .y = edge_attr bits (one 8B store per edge)
__global__ void csr_fill(const int* __restrict__ ei, const float* __restrict__ ea,
                         int* __restrict__ cur, int2* __restrict__ cse)
{
  int gid = blockIdx.x * 256 + threadIdx.x;
  if (gid >= T_STEPS * EE) return;
  int t = gid / EE, e = gid % EE;
  int src = ei[(size_t)t * 2 * EE + e];
  int dst = ei[(size_t)t * 2 * EE + EE + e];
  int slot = atomicAdd(&cur[t * NN + dst], 1);
  cse[(size_t)t * EE + slot] = make_int2(src, __float_as_int(ea[(size_t)t * EE + e]));
}

// ---------------------------------------------------------------------------
// GRU gate fusion. t0: gh == b_hh exactly (h0=0), h_prev=0.
// h_prev reconstructed from bf16 hi/lo split (error ~2^-18).
// ---------------------------------------------------------------------------
__global__ __launch_bounds__(256) void gru_gate(
    const float* __restrict__ gi, const float* __restrict__ gh,
    const float* __restrict__ b_hh, int t0,
    const unsigned short* __restrict__ phi, const unsigned short* __restrict__ plo,
    unsigned short* __restrict__ hhi_t, unsigned short* __restrict__ hlo_t)
{
  int idx = blockIdx.x * 256 + threadIdx.x;   // exact NN*DD grid
  int n = idx >> 7, d = idx & 127;
  size_t gb = (size_t)n * G3 + d;
  float ir = gi[gb], iz = gi[gb + DD], inn = gi[gb + 2 * DD];
  float hr, hz, hn, hp;
  if (t0) {
    hr = b_hh[d]; hz = b_hh[DD + d]; hn = b_hh[2 * DD + d]; hp = 0.f;
  } else {
    hr = gh[gb]; hz = gh[gb + DD]; hn = gh[gb + 2 * DD];
    hp = bf2f(phi[idx]) + bf2f(plo[idx]);
  }
  float r = 1.f / (1.f + __expf(-(ir + hr)));
  float z = 1.f / (1.f + __expf(-(iz + hz)));
  float nv = tanhf(inn + r * hn);
  float hnew = (1.f - z) * nv + z * hp;
  unsigned short hi, lo;
  bfsplit(hnew, hi, lo);
  hhi_t[idx] = hi; hlo_t[idx] = lo;
}

// ---------------------------------------------------------------------------
// Fused TransformerConv (d=128), 2 timesteps per launch via blockIdx.y.
// One wave per dst node; lane = (eslot 0..7) x (feature-group 0..7, 16 floats).
// 8 edges processed in parallel per chunk. Output: bf16 hi/lo split.
// ---------------------------------------------------------------------------
__global__ __launch_bounds__(256) void attn_conv(
    const float* __restrict__ qkvs2,  // [2][NN,512] (local pair buffer)
    const int* __restrict__ offs4,    // [T][NN+1]
    const int2* __restrict__ cse4,    // [T][E]
    const float* __restrict__ We,     // [128]
    int tbase,
    unsigned short* __restrict__ hhi4, unsigned short* __restrict__ hlo4)
{
  const int ty = blockIdx.y;
  const int t = tbase + ty;
  const float* qkvs = qkvs2 + (size_t)ty * NN * QS;
  const int* offs = offs4 + (size_t)t * (NN + 1);
  const int2* cse = cse4 + (size_t)t * EE;
  const int wv = (blockIdx.x * 256 + threadIdx.x) >> 6;
  const int lane = threadIdx.x & 63;
  if (wv >= NN) return;
  const int fg = lane & 7, es = lane >> 3;
  const int f0 = fg * 16;
  const float scale = 0.08838834764831845f;   // 1/sqrt(128)

  const float* qrow = &qkvs[(size_t)wv * QS];
  float4 q0 = *(const float4*)&qrow[f0 + 0];
  float4 q1 = *(const float4*)&qrow[f0 + 4];
  float4 q2 = *(const float4*)&qrow[f0 + 8];
  float4 q3 = *(const float4*)&qrow[f0 + 12];
  float4 w0 = *(const float4*)&We[f0 + 0];
  float4 w1 = *(const float4*)&We[f0 + 4];
  float4 w2 = *(const float4*)&We[f0 + 8];
  float4 w3 = *(const float4*)&We[f0 + 12];
  // q . We (per node)
  float qwe = q0.x * w0.x + q0.y * w0.y + q0.z * w0.z + q0.w * w0.w
            + q1.x * w1.x + q1.y * w1.y + q1.z * w1.z + q1.w * w1.w
            + q2.x * w2.x + q2.y * w2.y + q2.z * w2.z + q2.w * w2.w
            + q3.x * w3.x + q3.y * w3.y + q3.z * w3.z + q3.w * w3.w;
  qwe += __shfl_xor(qwe, 1); qwe += __shfl_xor(qwe, 2); qwe += __shfl_xor(qwe, 4);

  const int e0 = offs[wv], e1 = offs[wv + 1];
  float m_run = -INFINITY, l_run = 0.f;
  float acc[16];
#pragma unroll
  for (int i = 0; i < 16; ++i) acc[i] = 0.f;

  for (int base = e0; base < e1; base += 8) {
    const int eidx = base + es;
    const bool valid = eidx < e1;
    int2 se = valid ? cse[eidx] : make_int2(0, 0);
    const int s = se.x;
    const float a = __int_as_float(se.y);   // 0.0f when invalid
    const float* krow = &qkvs[(size_t)s * QS + 128];
    float4 k0 = *(const float4*)&krow[f0 + 0];
    float4 k1 = *(const float4*)&krow[f0 + 4];
    float4 k2 = *(const float4*)&krow[f0 + 8];
    float4 k3 = *(const float4*)&krow[f0 + 12];
    float p = q0.x * k0.x + q0.y * k0.y + q0.z * k0.z + q0.w * k0.w
            + q1.x * k1.x + q1.y * k1.y + q1.z * k1.z + q1.w * k1.w
            + q2.x * k2.x + q2.y * k2.y + q2.z * k2.z + q2.w * k2.w
            + q3.x * k3.x + q3.y * k3.y + q3.z * k3.z + q3.w * k3.w;
    p += __shfl_xor(p, 1); p += __shfl_xor(p, 2); p += __shfl_xor(p, 4);
    const float alpha = valid ? (p + a * qwe) * scale : -INFINITY;
    float cm = alpha;
    cm = fmaxf(cm, __shfl_xor(cm, 8));
    cm = fmaxf(cm, __shfl_xor(cm, 16));
    cm = fmaxf(cm, __shfl_xor(cm, 32));
    const float m_new = fmaxf(m_run, cm);
    const float fac = __expf(m_run - m_new);   // first chunk: exp(-inf)=0
    const float ex = __expf(alpha - m_new);    // invalid -> 0
    float sx = ex;
    sx += __shfl_xor(sx, 8); sx += __shfl_xor(sx, 16); sx += __shfl_xor(sx, 32);
    l_run = l_run * fac + sx;
    const float* vrow = &qkvs[(size_t)s * QS + 256];
    float4 v0 = *(const float4*)&vrow[f0 + 0];
    float4 v1 = *(const float4*)&vrow[f0 + 4];
    float4 v2 = *(const float4*)&vrow[f0 + 8];
    float4 v3 = *(const float4*)&vrow[f0 + 12];
    acc[0]  = acc[0]  * fac + ex * (v0.x + a * w0.x);
    acc[1]  = acc[1]  * fac + ex * (v0.y + a * w0.y);
    acc[2]  = acc[2]  * fac + ex * (v0.z + a * w0.z);
    acc[3]  = acc[3]  * fac + ex * (v0.w + a * w0.w);
    acc[4]  = acc[4]  * fac + ex * (v1.x + a * w1.x);
    acc[5]  = acc[5]  * fac + ex * (v1.y + a * w1.y);
    acc[6]  = acc[6]  * fac + ex * (v1.z + a * w1.z);
    acc[7]  = acc[7]  * fac + ex * (v1.w + a * w1.w);
    acc[8]  = acc[8]  * fac + ex * (v2.x + a * w2.x);
    acc[9]  = acc[9]  * fac + ex * (v2.y + a * w2.y);
    acc[10] = acc[10] * fac + ex * (v2.z + a * w2.z);
    acc[11] = acc[11] * fac + ex * (v2.w + a * w2.w);
    acc[12] = acc[12] * fac + ex * (v3.x + a * w3.x);
    acc[13] = acc[13] * fac + ex * (v3.y + a * w3.y);
    acc[14] = acc[14] * fac + ex * (v3.z + a * w3.z);
    acc[15] = acc[15] * fac + ex * (v3.w + a * w3.w);
    m_run = m_new;
  }
  // reduce accumulators over the 8 edge-slots
#pragma unroll
  for (int i = 0; i < 16; ++i) {
    acc[i] += __shfl_xor(acc[i], 8);
    acc[i] += __shfl_xor(acc[i], 16);
    acc[i] += __shfl_xor(acc[i], 32);
  }
  if (es != 0) return;
  const float inv = 1.f / (l_run + 1e-16f);
  const float* srow = &qkvs[(size_t)wv * QS + 384];
  float4 s0 = *(const float4*)&srow[f0 + 0];
  float4 s1 = *(const float4*)&srow[f0 + 4];
  float4 s2 = *(const float4*)&srow[f0 + 8];
  float4 s3 = *(const float4*)&srow[f0 + 12];
  float o[16];
  o[0] = acc[0] * inv + s0.x;  o[1] = acc[1] * inv + s0.y;
  o[2] = acc[2] * inv + s0.z;  o[3] = acc[3] * inv + s0.w;
  o[4] = acc[4] * inv + s1.x;  o[5] = acc[5] * inv + s1.y;
  o[6] = acc[6] * inv + s1.z;  o[7] = acc[7] * inv + s1.w;
  o[8] = acc[8] * inv + s2.x;  o[9] = acc[9] * inv + s2.y;
  o[10] = acc[10] * inv + s2.z; o[11] = acc[11] * inv + s2.w;
  o[12] = acc[12] * inv + s3.x; o[13] = acc[13] * inv + s3.y;
  o[14] = acc[14] * inv + s3.z; o[15] = acc[15] * inv + s3.w;
  unsigned hp[8], lp[8];
#pragma unroll
  for (int j = 0; j < 8; ++j) {
    float oa = o[2 * j], ob = o[2 * j + 1];
    oa = (oa > 0.f) ? oa : 0.01f * oa;    // leaky_relu
    ob = (ob > 0.f) ? ob : 0.01f * ob;
    unsigned short ha, la, hb, lb;
    bfsplit(oa, ha, la); bfsplit(ob, hb, lb);
    hp[j] = ((unsigned)hb << 16) | ha;
    lp[j] = ((unsigned)lb << 16) | la;
  }
  unsigned short* hdst = hhi4 + ((size_t)t * NN + wv) * DD + f0;
  unsigned short* ldst = hlo4 + ((size_t)t * NN + wv) * DD + f0;
  *(uint4*)(hdst + 0) = make_uint4(hp[0], hp[1], hp[2], hp[3]);
  *(uint4*)(hdst + 8) = make_uint4(hp[4], hp[5], hp[6], hp[7]);
  *(uint4*)(ldst + 0) = make_uint4(lp[0], lp[1], lp[2], lp[3]);
  *(uint4*)(ldst + 8) = make_uint4(lp[4], lp[5], lp[6], lp[7]);
}

// ---------------------------------------------------------------------------
// mean over T from bf16 hi/lo split (hi+lo ~= fp32); 2 elems per thread
// ---------------------------------------------------------------------------
__global__ void mean_k(const unsigned short* __restrict__ hhi,
                       const unsigned short* __restrict__ hlo,
                       float* __restrict__ hm)
{
  int i = blockIdx.x * 256 + threadIdx.x;   // exact NN*DD/2 grid
  float vx = 0.f, vy = 0.f;
#pragma unroll
  for (int t = 0; t < T_STEPS; ++t) {
    unsigned h = *(const unsigned*)&hhi[(size_t)t * NN * DD + 2 * i];
    unsigned l = *(const unsigned*)&hlo[(size_t)t * NN * DD + 2 * i];
    vx += __uint_as_float(h << 16) + __uint_as_float(l << 16);
    vy += __uint_as_float(h & 0xffff0000u) + __uint_as_float(l & 0xffff0000u);
  }
  *(float2*)&hm[2 * i] = make_float2(0.25f * vx, 0.25f * vy);
}

// ---------------------------------------------------------------------------
__global__ __launch_bounds__(256) void out_proj(
    const float* __restrict__ h,
    const float* __restrict__ Wq, const float* __restrict__ Wk,
    const float* __restrict__ Wv, const float* __restrict__ Ws,
    const float* __restrict__ bq, const float* __restrict__ bk,
    const float* __restrict__ bv, const float* __restrict__ bs,
    float* __restrict__ q1, float* __restrict__ k1,
    float* __restrict__ v1, float* __restrict__ s1)
{
  const int wv = (blockIdx.x * 256 + threadIdx.x) >> 6;
  const int lane = threadIdx.x & 63;
  if (wv >= NN) return;
  float2 h2 = *(const float2*)&h[(size_t)wv * DD + 2 * lane];
  float pq = h2.x * Wq[2 * lane] + h2.y * Wq[2 * lane + 1];
  float pk = h2.x * Wk[2 * lane] + h2.y * Wk[2 * lane + 1];
  float pv = h2.x * Wv[2 * lane] + h2.y * Wv[2 * lane + 1];
  float ps = h2.x * Ws[2 * lane] + h2.y * Ws[2 * lane + 1];
#pragma unroll
  for (int o = 1; o < 64; o <<= 1) {
    pq += __shfl_xor(pq, o); pk += __shfl_xor(pk, o);
    pv += __shfl_xor(pv, o); ps += __shfl_xor(ps, o);
  }
  if (lane == 0) {
    q1[wv] = pq + bq[0]; k1[wv] = pk + bk[0];
    v1[wv] = pv + bv[0]; s1[wv] = ps + bs[0];
  }
}

__global__ void out_attn(
    const float* __restrict__ q1, const float* __restrict__ k1,
    const float* __restrict__ v1, const float* __restrict__ s1,
    const int* __restrict__ offs, const int2* __restrict__ cse,
    const float* __restrict__ We, float* __restrict__ out)
{
  int n = blockIdx.x * 256 + threadIdx.x;
  if (n >= NN) return;
  const float we = We[0];
  const float q = q1[n];
  const int e0 = offs[n], e1 = offs[n + 1];
  float m = -INFINITY;
  for (int e = e0; e < e1; ++e) {
    int2 se = cse[e];
    float al = q * (k1[se.x] + __int_as_float(se.y) * we);
    m = fmaxf(m, al);
  }
  float l = 0.f, acc = 0.f;
  for (int e = e0; e < e1; ++e) {
    int2 se = cse[e];
    float ca = __int_as_float(se.y);
    float al = q * (k1[se.x] + ca * we);
    float ex = __expf(al - m);
    l += ex;
    acc += ex * (v1[se.x] + ca * we);
  }
  out[n] = acc / (l + 1e-16f) + s1[n];
}

// ---------------------------------------------------------------------------
extern "C" void kernel_launch(void* const* d_in, const int* in_sizes, int n_in,
                              void* d_out, int out_size, void* d_ws, size_t ws_size,
                              hipStream_t stream)
{
  const float* x_seq = (const float*)d_in[0];
  const int*   ei    = (const int*)  d_in[1];
  const float* ea    = (const float*)d_in[2];
  const float* W_ih  = (const float*)d_in[3];
  const float* W_hh  = (const float*)d_in[4];
  const float* b_ih  = (const float*)d_in[5];
  const float* b_hh  = (const float*)d_in[6];
  const float* cWq   = (const float*)d_in[7];
  const float* cbq   = (const float*)d_in[8];
  const float* cWk   = (const float*)d_in[9];
  const float* cbk   = (const float*)d_in[10];
  const float* cWv   = (const float*)d_in[11];
  const float* cbv   = (const float*)d_in[12];
  const float* cWe   = (const float*)d_in[13];
  const float* cWs   = (const float*)d_in[14];
  const float* cbs   = (const float*)d_in[15];
  const float* oWq   = (const float*)d_in[16];
  const float* obq   = (const float*)d_in[17];
  const float* oWk   = (const float*)d_in[18];
  const float* obk   = (const float*)d_in[19];
  const float* oWv   = (const float*)d_in[20];
  const float* obv   = (const float*)d_in[21];
  const float* oWe   = (const float*)d_in[22];
  const float* oWs   = (const float*)d_in[23];
  const float* obs   = (const float*)d_in[24];
  float* out = (float*)d_out;

  char* ws = (char*)d_ws;
  size_t off = 0;
  auto alloc = [&](size_t bytes) -> char* {
    char* p = ws + off;
    off += (bytes + 255) & ~(size_t)255;
    return p;
  };
  // ---- total workspace budget: ~171 MB (round-2's 186 MB is proven safe;
  //      round-3's 289 MB aborted => keep below) ----
  unsigned short* BihP  = (unsigned short*)alloc((size_t)2 * BIH_PAIRS * 2);
  unsigned short* BhhP  = (unsigned short*)alloc((size_t)2 * BHH_PAIRS * 2);
  unsigned short* WcatP = (unsigned short*)alloc((size_t)2 * WCAT_PAIRS * 2);
  float* fbcat = (float*)alloc((size_t)BCAT_N * 4);
  unsigned short* xhi   = (unsigned short*)alloc((size_t)T_STEPS * NN * IND * 2);
  unsigned short* xlo   = (unsigned short*)alloc((size_t)T_STEPS * NN * IND * 2);
  unsigned short* hallhi = (unsigned short*)alloc((size_t)T_STEPS * NN * DD * 2);
  unsigned short* halllo = (unsigned short*)alloc((size_t)T_STEPS * NN * DD * 2);
  float* fH    = (float*)alloc((size_t)NN * DD * 4);          // h_mean
  int*   iDeg  = (int*)  alloc((size_t)T_STEPS * NN * 4);     // zero-init
  int*   iCur  = (int*)  alloc((size_t)T_STEPS * NN * 4);
  int*   iOffs = (int*)  alloc((size_t)T_STEPS * (NN + 1) * 4);
  int*   iPart = (int*)  alloc((size_t)T_STEPS * NCHUNK * 4);
  int2*  iSE   = (int2*) alloc((size_t)T_STEPS * EE * 8);
  float* fQ1   = (float*)alloc((size_t)NN * 4);
  float* fK1   = (float*)alloc((size_t)NN * 4);
  float* fV1   = (float*)alloc((size_t)NN * 4);
  float* fS1   = (float*)alloc((size_t)NN * 4);
  // union region: GRU uses gi2 [2*NN*G3] + gh [NN*G3]; conv uses qkvs2 [2*NN*QS]
  size_t uniOff = off;
  float* fGi2  = (float*)(ws + uniOff);
  float* fGh   = (float*)(ws + uniOff + (size_t)2 * NN * G3 * 4);
  float* fQkvs2 = (float*)(ws + uniOff);
  (void)ws_size; (void)in_sizes; (void)n_in; (void)out_size;

  auto gemm = [&](const unsigned short* Ahi, const unsigned short* Alo,
                  const unsigned short* Bp, const float* bias, float* C,
                  int M, int N, int K) {
    int waves = (M >> 5) * (N >> 7);
    gemm_mfma<<<(waves + 3) / 4, 256, 0, stream>>>(Ahi, Alo, Bp, bias, C, M, N, K);
  };

  // weights + activation split + CSR
  pack_weights<<<(BIH_PAIRS + BHH_PAIRS + WCAT_PAIRS + BCAT_N + 255) / 256, 256, 0,
                 stream>>>(W_ih, W_hh, cWq, cWk, cWv, cWs, cbq, cbk, cbv, cbs,
                           BihP, BhhP, WcatP, fbcat);
  xsplit<<<(T_STEPS * NN * IND) / 256, 256, 0, stream>>>(x_seq, xhi, xlo);
  hipMemsetAsync(iDeg, 0, (size_t)T_STEPS * NN * 4, stream);
  csr_count<<<(T_STEPS * EE) / 256, 256, 0, stream>>>(ei, iDeg);
  scan1<<<T_STEPS * NCHUNK, 256, 0, stream>>>(iDeg, iPart);
  scan2<<<1, 128, 0, stream>>>(iPart, iOffs);
  scan3<<<T_STEPS * NCHUNK, 256, 0, stream>>>(iDeg, iPart, iOffs, iCur);
  csr_fill<<<(T_STEPS * EE) / 256, 256, 0, stream>>>(ei, ea, iCur, iSE);

  // GRU over time: gi batched in pairs of t, gh sequential (t=0 skipped)
  for (int tp = 0; tp < 2; ++tp) {
    gemm(xhi + (size_t)tp * 2 * NN * IND, xlo + (size_t)tp * 2 * NN * IND,
         BihP, b_ih, fGi2, 2 * NN, G3, IND);
    for (int k = 0; k < 2; ++k) {
      const int t = tp * 2 + k;
      const unsigned short* phi = hallhi + (size_t)(t - 1) * NN * DD;  // unused t=0
      const unsigned short* plo = halllo + (size_t)(t - 1) * NN * DD;
      if (t > 0) gemm(phi, plo, BhhP, b_hh, fGh, NN, G3, DD);
      gru_gate<<<(NN * DD) / 256, 256, 0, stream>>>(
          fGi2 + (size_t)k * NN * G3, fGh, b_hh, (t == 0) ? 1 : 0,
          (t == 0) ? hallhi : phi, (t == 0) ? halllo : plo,
          hallhi + (size_t)t * NN * DD, halllo + (size_t)t * NN * DD);
    }
  }

  // stacked TransformerConv layers, pairs of timesteps
  for (int l = 0; l < 2; ++l) {
    for (int tp = 0; tp < 2; ++tp) {
      const int tb = tp * 2;
      gemm(hallhi + (size_t)tb * NN * DD, halllo + (size_t)tb * NN * DD,
           WcatP + (size_t)l * 131072, fbcat + (size_t)l * QS,
           fQkvs2, 2 * NN, QS, DD);
      dim3 ag((NN * 64) / 256, 2);
      attn_conv<<<ag, 256, 0, stream>>>(fQkvs2, iOffs, iSE, cWe + l * DD, tb,
                                        hallhi, halllo);
    }
  }

  // mean over T (reconstruct fp32 from hi+lo)
  mean_k<<<(NN * DD / 2) / 256, 256, 0, stream>>>(hallhi, halllo, fH);

  // output conv (d=1) on t=3 graph
  out_proj<<<(NN * 64) / 256, 256, 0, stream>>>(
      fH, oWq, oWk, oWv, oWs, obq, obk, obv, obs, fQ1, fK1, fV1, fS1);
  out_attn<<<(NN + 255) / 256, 256, 0, stream>>>(
      fQ1, fK1, fV1, fS1, iOffs + 3 * (NN + 1), iSE + (size_t)3 * EE, oWe, out);
}

// Round 5
// 661.410 us; speedup vs baseline: 2.3301x; 1.1167x over previous
//
#include <hip/hip_runtime.h>
#include <math.h>

#define T_STEPS 4
#define NN 20000
#define EE 160000
#define IND 64
#define DD 128
#define G3 384     // 3*D (GRU gates)
#define QS 512     // q|k|v|skip fused width

typedef __bf16 bf16x8 __attribute__((ext_vector_type(8)));
typedef float floatx4 __attribute__((ext_vector_type(4)));

// ---------------------------------------------------------------------------
// fp32 -> bf16 split (RNE): x ~= hi + lo, |x-(hi+lo)| <~ 2^-18 |x|
// ---------------------------------------------------------------------------
__device__ inline unsigned short f2bf(float x) {
  unsigned u = __float_as_uint(x);
  unsigned r = (u + 0x7fffu + ((u >> 16) & 1u)) >> 16;
  return (unsigned short)r;
}
__device__ inline float bf2f(unsigned short h) {
  return __uint_as_float((unsigned)h << 16);
}
__device__ inline void bfsplit(float x, unsigned short& hi, unsigned short& lo) {
  hi = f2bf(x);
  lo = f2bf(x - bf2f(hi));
}
// load 16 consecutive bf16 -> fp32 (32B, two dwordx4)
__device__ inline void ld16bf(const unsigned short* p, float* f) {
  const uint4 u0 = *(const uint4*)p;
  const uint4 u1 = *(const uint4*)(p + 8);
  f[0] = __uint_as_float(u0.x << 16);  f[1] = __uint_as_float(u0.x & 0xffff0000u);
  f[2] = __uint_as_float(u0.y << 16);  f[3] = __uint_as_float(u0.y & 0xffff0000u);
  f[4] = __uint_as_float(u0.z << 16);  f[5] = __uint_as_float(u0.z & 0xffff0000u);
  f[6] = __uint_as_float(u0.w << 16);  f[7] = __uint_as_float(u0.w & 0xffff0000u);
  f[8]  = __uint_as_float(u1.x << 16); f[9]  = __uint_as_float(u1.x & 0xffff0000u);
  f[10] = __uint_as_float(u1.y << 16); f[11] = __uint_as_float(u1.y & 0xffff0000u);
  f[12] = __uint_as_float(u1.z << 16); f[13] = __uint_as_float(u1.z & 0xffff0000u);
  f[14] = __uint_as_float(u1.w << 16); f[15] = __uint_as_float(u1.w & 0xffff0000u);
}

// ---------------------------------------------------------------------------
// Split-bf16 MFMA GEMM: C[M,N] = (Ahi+Alo)[M,K] x B + bias.
// obf16=0 -> fp32 C ; obf16=1 -> bf16 Cb (RNE). Wave: 32 rows x 128 cols.
// ---------------------------------------------------------------------------
__global__ __launch_bounds__(256) void gemm_mfma(
    const unsigned short* __restrict__ Ahi, const unsigned short* __restrict__ Alo,
    const unsigned short* __restrict__ Bp, const float* __restrict__ bias,
    float* __restrict__ C, unsigned short* __restrict__ Cb,
    int M, int N, int K, int obf16)
{
  const int wave = (blockIdx.x * 256 + threadIdx.x) >> 6;
  const int lane = threadIdx.x & 63;
  const int ngroups = N >> 7;          // N/128
  const int mtiles = M >> 5;           // 32 rows per wave
  if (wave >= mtiles * ngroups) return;
  const int mw = wave / ngroups;
  const int ng = wave - mw * ngroups;
  const int r = lane & 15, quad = lane >> 4;
  const int ktiles = K >> 5;
  const unsigned short* a0h = Ahi + (size_t)(mw * 32 + r) * K + quad * 8;
  const unsigned short* a0l = Alo + (size_t)(mw * 32 + r) * K + quad * 8;
  const unsigned short* a1h = a0h + (size_t)16 * K;
  const unsigned short* a1l = a0l + (size_t)16 * K;
  floatx4 acc[2][8];
#pragma unroll
  for (int m = 0; m < 2; ++m)
#pragma unroll
    for (int nt = 0; nt < 8; ++nt) acc[m][nt] = (floatx4){0.f, 0.f, 0.f, 0.f};
  const int n0t = ng * 8;
  for (int kt = 0; kt < ktiles; ++kt) {
    bf16x8 a0hi = *(const bf16x8*)(a0h + kt * 32);
    bf16x8 a0lo = *(const bf16x8*)(a0l + kt * 32);
    bf16x8 a1hi = *(const bf16x8*)(a1h + kt * 32);
    bf16x8 a1lo = *(const bf16x8*)(a1l + kt * 32);
#pragma unroll
    for (int nt = 0; nt < 8; ++nt) {
      const unsigned short* bp =
          Bp + ((size_t)((n0t + nt) * ktiles + kt)) * 1024 + lane * 8;
      bf16x8 bhi = *(const bf16x8*)bp;
      bf16x8 blo = *(const bf16x8*)(bp + 512);
      acc[0][nt] = __builtin_amdgcn_mfma_f32_16x16x32_bf16(a0hi, bhi, acc[0][nt], 0, 0, 0);
      acc[0][nt] = __builtin_amdgcn_mfma_f32_16x16x32_bf16(a0hi, blo, acc[0][nt], 0, 0, 0);
      acc[0][nt] = __builtin_amdgcn_mfma_f32_16x16x32_bf16(a0lo, bhi, acc[0][nt], 0, 0, 0);
      acc[1][nt] = __builtin_amdgcn_mfma_f32_16x16x32_bf16(a1hi, bhi, acc[1][nt], 0, 0, 0);
      acc[1][nt] = __builtin_amdgcn_mfma_f32_16x16x32_bf16(a1hi, blo, acc[1][nt], 0, 0, 0);
      acc[1][nt] = __builtin_amdgcn_mfma_f32_16x16x32_bf16(a1lo, bhi, acc[1][nt], 0, 0, 0);
    }
  }
#pragma unroll
  for (int m = 0; m < 2; ++m) {
    const int crow0 = mw * 32 + m * 16 + quad * 4;
#pragma unroll
    for (int nt = 0; nt < 8; ++nt) {
      const int col = ng * 128 + nt * 16 + r;
      const float b = bias[col];
      if (obf16) {
#pragma unroll
        for (int i = 0; i < 4; ++i)
          Cb[(size_t)(crow0 + i) * N + col] = f2bf(acc[m][nt][i] + b);
      } else {
#pragma unroll
        for (int i = 0; i < 4; ++i)
          C[(size_t)(crow0 + i) * N + col] = acc[m][nt][i] + b;
      }
    }
  }
}

// ---------------------------------------------------------------------------
// Weight packing into MFMA fragment order (hi/lo split) + fused conv bias
// ---------------------------------------------------------------------------
#define BIH_PAIRS 24576    // (384/16)*(64/32)*512
#define BHH_PAIRS 49152    // 24*4*512
#define WCAT_PAIRS 131072  // 2*32*4*512
#define BCAT_N 1024

__global__ void pack_weights(
    const float* __restrict__ Wih, const float* __restrict__ Whh,
    const float* __restrict__ Wq, const float* __restrict__ Wk,
    const float* __restrict__ Wv, const float* __restrict__ Ws,
    const float* __restrict__ bq, const float* __restrict__ bk,
    const float* __restrict__ bv, const float* __restrict__ bs,
    unsigned short* __restrict__ BihP, unsigned short* __restrict__ BhhP,
    unsigned short* __restrict__ WcatP, float* __restrict__ bcat)
{
  int gid = blockIdx.x * 256 + threadIdx.x;
  if (gid < BIH_PAIRS) {  // K=64, N=384, ktiles=2
    int tile = gid >> 9, lj = gid & 511, lane = lj >> 3, j = lj & 7;
    int k_tile = tile & 1, n_tile = tile >> 1;
    int n = n_tile * 16 + (lane & 15);
    int k = k_tile * 32 + (lane >> 4) * 8 + j;
    unsigned short hi, lo;
    bfsplit(Wih[n * IND + k], hi, lo);   // B[k][n] = Wih^T
    BihP[tile * 1024 + lane * 8 + j] = hi;
    BihP[tile * 1024 + 512 + lane * 8 + j] = lo;
    return;
  }
  gid -= BIH_PAIRS;
  if (gid < BHH_PAIRS) {  // K=128, N=384, ktiles=4
    int tile = gid >> 9, lj = gid & 511, lane = lj >> 3, j = lj & 7;
    int k_tile = tile & 3, n_tile = tile >> 2;
    int n = n_tile * 16 + (lane & 15);
    int k = k_tile * 32 + (lane >> 4) * 8 + j;
    unsigned short hi, lo;
    bfsplit(Whh[n * DD + k], hi, lo);
    BhhP[tile * 1024 + lane * 8 + j] = hi;
    BhhP[tile * 1024 + 512 + lane * 8 + j] = lo;
    return;
  }
  gid -= BHH_PAIRS;
  if (gid < WCAT_PAIRS) {  // per layer: K=128, N=512, ktiles=4
    int l = gid >> 16, rem = gid & 65535;
    int tile = rem >> 9, lj = rem & 511, lane = lj >> 3, j = lj & 7;
    int k_tile = tile & 3, n_tile = tile >> 2;
    int n = n_tile * 16 + (lane & 15);
    int k = k_tile * 32 + (lane >> 4) * 8 + j;
    const float* W = (n < 128) ? Wq : (n < 256) ? Wk : (n < 384) ? Wv : Ws;
    unsigned short hi, lo;
    bfsplit(W[l * DD * DD + k * DD + (n & 127)], hi, lo);
    size_t base = (size_t)l * 131072 + tile * 1024;
    WcatP[base + lane * 8 + j] = hi;
    WcatP[base + 512 + lane * 8 + j] = lo;
    return;
  }
  gid -= WCAT_PAIRS;
  if (gid < BCAT_N) {
    int l = gid >> 9, n = gid & 511;
    const float* b = (n < 128) ? bq : (n < 256) ? bk : (n < 384) ? bv : bs;
    bcat[gid] = b[l * DD + (n & 127)];
  }
}

// ---------------------------------------------------------------------------
__global__ void xsplit(const float* __restrict__ x,
                       unsigned short* __restrict__ xhi,
                       unsigned short* __restrict__ xlo)
{
  int i = blockIdx.x * 256 + threadIdx.x;   // exact T*NN*IND grid
  unsigned short hi, lo;
  bfsplit(x[i], hi, lo);
  xhi[i] = hi; xlo[i] = lo;
}

// ---------------------------------------------------------------------------
// CSR build (by destination), per timestep; parallel 3-phase scan
// ---------------------------------------------------------------------------
#define SCHUNK 1024
#define NCHUNK 20          // ceil(20000/1024)

__global__ void csr_count(const int* __restrict__ ei, int* __restrict__ deg)
{
  int gid = blockIdx.x * 256 + threadIdx.x;
  if (gid >= T_STEPS * EE) return;
  int t = gid / EE, e = gid % EE;
  int dst = ei[(size_t)t * 2 * EE + EE + e];
  atomicAdd(&deg[t * NN + dst], 1);
}

__global__ void scan1(const int* __restrict__ deg, int* __restrict__ part)
{
  const int b = blockIdx.x;              // 0..T*NCHUNK-1
  const int t = b / NCHUNK, c = b % NCHUNK;
  const int tid = threadIdx.x;
  __shared__ int s[256];
  int base = c * SCHUNK + tid * 4;
  int sum = 0;
#pragma unroll
  for (int u = 0; u < 4; ++u) {
    int i = base + u;
    if (i < NN) sum += deg[t * NN + i];
  }
  s[tid] = sum;
  __syncthreads();
  for (int o = 128; o > 0; o >>= 1) {
    if (tid < o) s[tid] += s[tid + o];
    __syncthreads();
  }
  if (tid == 0) part[b] = s[0];
}

__global__ void scan2(int* __restrict__ part, int* __restrict__ offs)
{
  const int tid = threadIdx.x;
  __shared__ int s[T_STEPS * NCHUNK];
  if (tid < T_STEPS * NCHUNK) s[tid] = part[tid];
  __syncthreads();
  if (tid == 0) {
    for (int t = 0; t < T_STEPS; ++t) {
      int run = 0;
      for (int c = 0; c < NCHUNK; ++c) {
        int v = s[t * NCHUNK + c];
        s[t * NCHUNK + c] = run;
        run += v;
      }
      offs[t * (NN + 1) + NN] = run;
    }
  }
  __syncthreads();
  if (tid < T_STEPS * NCHUNK) part[tid] = s[tid];
}

__global__ void scan3(const int* __restrict__ deg, const int* __restrict__ part,
                      int* __restrict__ offs, int* __restrict__ cur)
{
  const int b = blockIdx.x;
  const int t = b / NCHUNK, c = b % NCHUNK;
  const int tid = threadIdx.x;
  __shared__ int s[256];
  int base = c * SCHUNK + tid * 4;
  int v[4]; int sum = 0;
#pragma unroll
  for (int u = 0; u < 4; ++u) {
    int i = base + u;
    v[u] = (i < NN) ? deg[t * NN + i] : 0;
    sum += v[u];
  }
  s[tid] = sum;
  __syncthreads();
  for (int o = 1; o < 256; o <<= 1) {
    int x = (tid >= o) ? s[tid - o] : 0;
    __syncthreads();
    s[tid] += x;
    __syncthreads();
  }
  int excl = part[b] + s[tid] - sum;
#pragma unroll
  for (int u = 0; u < 4; ++u) {
    int i = base + u;
    if (i < NN) {
      offs[t * (NN + 1) + i] = excl;
      cur[t * NN + i] = excl;
    }
    excl += v[u];
  }
}

// packed CSR entry: .x = src node, .y = edge_attr bits (one 8B store per edge)
__global__ void csr_fill(const int* __restrict__ ei, const float* __restrict__ ea,
                         int* __restrict__ cur, int2* __restrict__ cse)
{
  int gid = blockIdx.x * 256 + threadIdx.x;
  if (gid >= T_STEPS * EE) return;
  int t = gid / EE, e = gid % EE;
  int src = ei[(size_t)t * 2 * EE + e];
  int dst = ei[(size_t)t * 2 * EE + EE + e];
  int slot = atomicAdd(&cur[t * NN + dst], 1);
  cse[(size_t)t * EE + slot] = make_int2(src, __float_as_int(ea[(size_t)t * EE + e]));
}

// ---------------------------------------------------------------------------
// GRU gate fusion. t0: gh == b_hh exactly (h0=0), h_prev=0.
// ---------------------------------------------------------------------------
__global__ __launch_bounds__(256) void gru_gate(
    const float* __restrict__ gi, const float* __restrict__ gh,
    const float* __restrict__ b_hh, int t0,
    const unsigned short* __restrict__ phi, const unsigned short* __restrict__ plo,
    unsigned short* __restrict__ hhi_t, unsigned short* __restrict__ hlo_t)
{
  int idx = blockIdx.x * 256 + threadIdx.x;   // exact NN*DD grid
  int n = idx >> 7, d = idx & 127;
  size_t gb = (size_t)n * G3 + d;
  float ir = gi[gb], iz = gi[gb + DD], inn = gi[gb + 2 * DD];
  float hr, hz, hn, hp;
  if (t0) {
    hr = b_hh[d]; hz = b_hh[DD + d]; hn = b_hh[2 * DD + d]; hp = 0.f;
  } else {
    hr = gh[gb]; hz = gh[gb + DD]; hn = gh[gb + 2 * DD];
    hp = bf2f(phi[idx]) + bf2f(plo[idx]);
  }
  float r = 1.f / (1.f + __expf(-(ir + hr)));
  float z = 1.f / (1.f + __expf(-(iz + hz)));
  float nv = tanhf(inn + r * hn);
  float hnew = (1.f - z) * nv + z * hp;
  unsigned short hi, lo;
  bfsplit(hnew, hi, lo);
  hhi_t[idx] = hi; hlo_t[idx] = lo;
}

// ---------------------------------------------------------------------------
// Fused TransformerConv (d=128), all T via blockIdx.y. qkvb is bf16 [T][NN][512].
// One wave per dst node; lane = (eslot 0..7) x (feature-group 0..7, 16 floats).
// Output: bf16 hi/lo split (next GEMM input + mean).
// ---------------------------------------------------------------------------
__global__ __launch_bounds__(256) void attn_conv(
    const unsigned short* __restrict__ qkvb,  // [T][NN][512] bf16
    const int* __restrict__ offs4,    // [T][NN+1]
    const int2* __restrict__ cse4,    // [T][E]
    const float* __restrict__ We,     // [128]
    unsigned short* __restrict__ hhi4, unsigned short* __restrict__ hlo4)
{
  const int t = blockIdx.y;
  const unsigned short* qk = qkvb + (size_t)t * NN * QS;
  const int* offs = offs4 + (size_t)t * (NN + 1);
  const int2* cse = cse4 + (size_t)t * EE;
  const int wv = (blockIdx.x * 256 + threadIdx.x) >> 6;
  const int lane = threadIdx.x & 63;
  if (wv >= NN) return;
  const int fg = lane & 7, es = lane >> 3;
  const int f0 = fg * 16;
  const float scale = 0.08838834764831845f;   // 1/sqrt(128)

  float qf[16], wf[16];
  ld16bf(qk + (size_t)wv * QS + f0, qf);
#pragma unroll
  for (int j = 0; j < 16; j += 4)
    *(float4*)&wf[j] = *(const float4*)&We[f0 + j];
  float qwe = 0.f;
#pragma unroll
  for (int j = 0; j < 16; ++j) qwe = fmaf(qf[j], wf[j], qwe);
  qwe += __shfl_xor(qwe, 1); qwe += __shfl_xor(qwe, 2); qwe += __shfl_xor(qwe, 4);

  const int e0 = offs[wv], e1 = offs[wv + 1];
  float m_run = -INFINITY, l_run = 0.f;
  float acc[16];
#pragma unroll
  for (int i = 0; i < 16; ++i) acc[i] = 0.f;

  for (int base = e0; base < e1; base += 8) {
    const int eidx = base + es;
    const bool valid = eidx < e1;
    int2 se = valid ? cse[eidx] : make_int2(0, 0);
    const int s = se.x;
    const float a = __int_as_float(se.y);   // 0.0f when invalid
    float kf[16];
    ld16bf(qk + (size_t)s * QS + 128 + f0, kf);
    float p = 0.f;
#pragma unroll
    for (int j = 0; j < 16; ++j) p = fmaf(qf[j], kf[j], p);
    p += __shfl_xor(p, 1); p += __shfl_xor(p, 2); p += __shfl_xor(p, 4);
    const float alpha = valid ? (p + a * qwe) * scale : -INFINITY;
    float cm = alpha;
    cm = fmaxf(cm, __shfl_xor(cm, 8));
    cm = fmaxf(cm, __shfl_xor(cm, 16));
    cm = fmaxf(cm, __shfl_xor(cm, 32));
    const float m_new = fmaxf(m_run, cm);
    const float fac = __expf(m_run - m_new);   // first chunk: exp(-inf)=0
    const float ex = __expf(alpha - m_new);    // invalid -> 0
    float sx = ex;
    sx += __shfl_xor(sx, 8); sx += __shfl_xor(sx, 16); sx += __shfl_xor(sx, 32);
    l_run = l_run * fac + sx;
    float vf[16];
    ld16bf(qk + (size_t)s * QS + 256 + f0, vf);
#pragma unroll
    for (int j = 0; j < 16; ++j)
      acc[j] = fmaf(acc[j], fac, ex * fmaf(a, wf[j], vf[j]));
    m_run = m_new;
  }
  // reduce accumulators over the 8 edge-slots
#pragma unroll
  for (int i = 0; i < 16; ++i) {
    acc[i] += __shfl_xor(acc[i], 8);
    acc[i] += __shfl_xor(acc[i], 16);
    acc[i] += __shfl_xor(acc[i], 32);
  }
  if (es != 0) return;
  const float inv = 1.f / (l_run + 1e-16f);
  float sf[16];
  ld16bf(qk + (size_t)wv * QS + 384 + f0, sf);
  unsigned hp[8], lp[8];
#pragma unroll
  for (int j = 0; j < 8; ++j) {
    float oa = acc[2 * j] * inv + sf[2 * j];
    float ob = acc[2 * j + 1] * inv + sf[2 * j + 1];
    oa = (oa > 0.f) ? oa : 0.01f * oa;    // leaky_relu
    ob = (ob > 0.f) ? ob : 0.01f * ob;
    unsigned short ha, la, hb, lb;
    bfsplit(oa, ha, la); bfsplit(ob, hb, lb);
    hp[j] = ((unsigned)hb << 16) | ha;
    lp[j] = ((unsigned)lb << 16) | la;
  }
  unsigned short* hdst = hhi4 + ((size_t)t * NN + wv) * DD + f0;
  unsigned short* ldst = hlo4 + ((size_t)t * NN + wv) * DD + f0;
  *(uint4*)(hdst + 0) = make_uint4(hp[0], hp[1], hp[2], hp[3]);
  *(uint4*)(hdst + 8) = make_uint4(hp[4], hp[5], hp[6], hp[7]);
  *(uint4*)(ldst + 0) = make_uint4(lp[0], lp[1], lp[2], lp[3]);
  *(uint4*)(ldst + 8) = make_uint4(lp[4], lp[5], lp[6], lp[7]);
}

// ---------------------------------------------------------------------------
// mean over T from bf16 hi/lo split (hi+lo ~= fp32); 2 elems per thread
// ---------------------------------------------------------------------------
__global__ void mean_k(const unsigned short* __restrict__ hhi,
                       const unsigned short* __restrict__ hlo,
                       float* __restrict__ hm)
{
  int i = blockIdx.x * 256 + threadIdx.x;   // exact NN*DD/2 grid
  float vx = 0.f, vy = 0.f;
#pragma unroll
  for (int t = 0; t < T_STEPS; ++t) {
    unsigned h = *(const unsigned*)&hhi[(size_t)t * NN * DD + 2 * i];
    unsigned l = *(const unsigned*)&hlo[(size_t)t * NN * DD + 2 * i];
    vx += __uint_as_float(h << 16) + __uint_as_float(l << 16);
    vy += __uint_as_float(h & 0xffff0000u) + __uint_as_float(l & 0xffff0000u);
  }
  *(float2*)&hm[2 * i] = make_float2(0.25f * vx, 0.25f * vy);
}

// ---------------------------------------------------------------------------
__global__ __launch_bounds__(256) void out_proj(
    const float* __restrict__ h,
    const float* __restrict__ Wq, const float* __restrict__ Wk,
    const float* __restrict__ Wv, const float* __restrict__ Ws,
    const float* __restrict__ bq, const float* __restrict__ bk,
    const float* __restrict__ bv, const float* __restrict__ bs,
    float* __restrict__ q1, float* __restrict__ k1,
    float* __restrict__ v1, float* __restrict__ s1)
{
  const int wv = (blockIdx.x * 256 + threadIdx.x) >> 6;
  const int lane = threadIdx.x & 63;
  if (wv >= NN) return;
  float2 h2 = *(const float2*)&h[(size_t)wv * DD + 2 * lane];
  float pq = h2.x * Wq[2 * lane] + h2.y * Wq[2 * lane + 1];
  float pk = h2.x * Wk[2 * lane] + h2.y * Wk[2 * lane + 1];
  float pv = h2.x * Wv[2 * lane] + h2.y * Wv[2 * lane + 1];
  float ps = h2.x * Ws[2 * lane] + h2.y * Ws[2 * lane + 1];
#pragma unroll
  for (int o = 1; o < 64; o <<= 1) {
    pq += __shfl_xor(pq, o); pk += __shfl_xor(pk, o);
    pv += __shfl_xor(pv, o); ps += __shfl_xor(ps, o);
  }
  if (lane == 0) {
    q1[wv] = pq + bq[0]; k1[wv] = pk + bk[0];
    v1[wv] = pv + bv[0]; s1[wv] = ps + bs[0];
  }
}

__global__ void out_attn(
    const float* __restrict__ q1, const float* __restrict__ k1,
    const float* __restrict__ v1, const float* __restrict__ s1,
    const int* __restrict__ offs, const int2* __restrict__ cse,
    const float* __restrict__ We, float* __restrict__ out)
{
  int n = blockIdx.x * 256 + threadIdx.x;
  if (n >= NN) return;
  const float we = We[0];
  const float q = q1[n];
  const int e0 = offs[n], e1 = offs[n + 1];
  float m = -INFINITY;
  for (int e = e0; e < e1; ++e) {
    int2 se = cse[e];
    float al = q * (k1[se.x] + __int_as_float(se.y) * we);
    m = fmaxf(m, al);
  }
  float l = 0.f, acc = 0.f;
  for (int e = e0; e < e1; ++e) {
    int2 se = cse[e];
    float ca = __int_as_float(se.y);
    float al = q * (k1[se.x] + ca * we);
    float ex = __expf(al - m);
    l += ex;
    acc += ex * (v1[se.x] + ca * we);
  }
  out[n] = acc / (l + 1e-16f) + s1[n];
}

// ---------------------------------------------------------------------------
extern "C" void kernel_launch(void* const* d_in, const int* in_sizes, int n_in,
                              void* d_out, int out_size, void* d_ws, size_t ws_size,
                              hipStream_t stream)
{
  const float* x_seq = (const float*)d_in[0];
  const int*   ei    = (const int*)  d_in[1];
  const float* ea    = (const float*)d_in[2];
  const float* W_ih  = (const float*)d_in[3];
  const float* W_hh  = (const float*)d_in[4];
  const float* b_ih  = (const float*)d_in[5];
  const float* b_hh  = (const float*)d_in[6];
  const float* cWq   = (const float*)d_in[7];
  const float* cbq   = (const float*)d_in[8];
  const float* cWk   = (const float*)d_in[9];
  const float* cbk   = (const float*)d_in[10];
  const float* cWv   = (const float*)d_in[11];
  const float* cbv   = (const float*)d_in[12];
  const float* cWe   = (const float*)d_in[13];
  const float* cWs   = (const float*)d_in[14];
  const float* cbs   = (const float*)d_in[15];
  const float* oWq   = (const float*)d_in[16];
  const float* obq   = (const float*)d_in[17];
  const float* oWk   = (const float*)d_in[18];
  const float* obk   = (const float*)d_in[19];
  const float* oWv   = (const float*)d_in[20];
  const float* obv   = (const float*)d_in[21];
  const float* oWe   = (const float*)d_in[22];
  const float* oWs   = (const float*)d_in[23];
  const float* obs   = (const float*)d_in[24];
  float* out = (float*)d_out;

  char* ws = (char*)d_ws;
  size_t off = 0;
  auto alloc = [&](size_t bytes) -> char* {
    char* p = ws + off;
    off += (bytes + 255) & ~(size_t)255;
    return p;
  };
  // ---- total ~171 MB (round-4 proven; round-3's 289 MB aborted) ----
  unsigned short* BihP  = (unsigned short*)alloc((size_t)2 * BIH_PAIRS * 2);
  unsigned short* BhhP  = (unsigned short*)alloc((size_t)2 * BHH_PAIRS * 2);
  unsigned short* WcatP = (unsigned short*)alloc((size_t)2 * WCAT_PAIRS * 2);
  float* fbcat = (float*)alloc((size_t)BCAT_N * 4);
  unsigned short* xhi   = (unsigned short*)alloc((size_t)T_STEPS * NN * IND * 2);
  unsigned short* xlo   = (unsigned short*)alloc((size_t)T_STEPS * NN * IND * 2);
  unsigned short* hallhi = (unsigned short*)alloc((size_t)T_STEPS * NN * DD * 2);
  unsigned short* halllo = (unsigned short*)alloc((size_t)T_STEPS * NN * DD * 2);
  float* fH    = (float*)alloc((size_t)NN * DD * 4);          // h_mean
  int*   iDeg  = (int*)  alloc((size_t)T_STEPS * NN * 4);     // zero-init
  int*   iCur  = (int*)  alloc((size_t)T_STEPS * NN * 4);
  int*   iOffs = (int*)  alloc((size_t)T_STEPS * (NN + 1) * 4);
  int*   iPart = (int*)  alloc((size_t)T_STEPS * NCHUNK * 4);
  int2*  iSE   = (int2*) alloc((size_t)T_STEPS * EE * 8);
  float* fQ1   = (float*)alloc((size_t)NN * 4);
  float* fK1   = (float*)alloc((size_t)NN * 4);
  float* fV1   = (float*)alloc((size_t)NN * 4);
  float* fS1   = (float*)alloc((size_t)NN * 4);
  // union: GRU uses gi2 [2NN*G3 fp32] + gh [NN*G3 fp32] = 92.2 MB;
  //        conv uses qkvb [4NN*512 bf16] = 81.9 MB
  size_t uniOff = off;
  float* fGi2  = (float*)(ws + uniOff);
  float* fGh   = (float*)(ws + uniOff + (size_t)2 * NN * G3 * 4);
  unsigned short* qkvb = (unsigned short*)(ws + uniOff);
  (void)ws_size; (void)in_sizes; (void)n_in; (void)out_size;

  auto gemm = [&](const unsigned short* Ahi, const unsigned short* Alo,
                  const unsigned short* Bp, const float* bias, float* C,
                  unsigned short* Cb, int M, int N, int K, int obf16) {
    int waves = (M >> 5) * (N >> 7);
    gemm_mfma<<<(waves + 3) / 4, 256, 0, stream>>>(Ahi, Alo, Bp, bias, C, Cb,
                                                   M, N, K, obf16);
  };

  // weights + activation split + CSR
  pack_weights<<<(BIH_PAIRS + BHH_PAIRS + WCAT_PAIRS + BCAT_N + 255) / 256, 256, 0,
                 stream>>>(W_ih, W_hh, cWq, cWk, cWv, cWs, cbq, cbk, cbv, cbs,
                           BihP, BhhP, WcatP, fbcat);
  xsplit<<<(T_STEPS * NN * IND) / 256, 256, 0, stream>>>(x_seq, xhi, xlo);
  hipMemsetAsync(iDeg, 0, (size_t)T_STEPS * NN * 4, stream);
  csr_count<<<(T_STEPS * EE) / 256, 256, 0, stream>>>(ei, iDeg);
  scan1<<<T_STEPS * NCHUNK, 256, 0, stream>>>(iDeg, iPart);
  scan2<<<1, 128, 0, stream>>>(iPart, iOffs);
  scan3<<<T_STEPS * NCHUNK, 256, 0, stream>>>(iDeg, iPart, iOffs, iCur);
  csr_fill<<<(T_STEPS * EE) / 256, 256, 0, stream>>>(ei, ea, iCur, iSE);

  // GRU over time: gi batched in pairs of t, gh sequential (t=0 skipped)
  for (int tp = 0; tp < 2; ++tp) {
    gemm(xhi + (size_t)tp * 2 * NN * IND, xlo + (size_t)tp * 2 * NN * IND,
         BihP, b_ih, fGi2, nullptr, 2 * NN, G3, IND, 0);
    for (int k = 0; k < 2; ++k) {
      const int t = tp * 2 + k;
      const unsigned short* phi = hallhi + (size_t)(t - 1) * NN * DD;  // unused t=0
      const unsigned short* plo = halllo + (size_t)(t - 1) * NN * DD;
      if (t > 0) gemm(phi, plo, BhhP, b_hh, fGh, nullptr, NN, G3, DD, 0);
      gru_gate<<<(NN * DD) / 256, 256, 0, stream>>>(
          fGi2 + (size_t)k * NN * G3, fGh, b_hh, (t == 0) ? 1 : 0,
          (t == 0) ? hallhi : phi, (t == 0) ? halllo : plo,
          hallhi + (size_t)t * NN * DD, halllo + (size_t)t * NN * DD);
    }
  }

  // stacked TransformerConv layers, full T batch, bf16 qkvb
  for (int l = 0; l < 2; ++l) {
    gemm(hallhi, halllo, WcatP + (size_t)l * 131072, fbcat + (size_t)l * QS,
         nullptr, qkvb, T_STEPS * NN, QS, DD, 1);
    dim3 ag((NN * 64) / 256, T_STEPS);
    attn_conv<<<ag, 256, 0, stream>>>(qkvb, iOffs, iSE, cWe + l * DD,
                                      hallhi, halllo);
  }

  // mean over T (reconstruct fp32 from hi+lo)
  mean_k<<<(NN * DD / 2) / 256, 256, 0, stream>>>(hallhi, halllo, fH);

  // output conv (d=1) on t=3 graph
  out_proj<<<(NN * 64) / 256, 256, 0, stream>>>(
      fH, oWq, oWk, oWv, oWs, obq, obk, obv, obs, fQ1, fK1, fV1, fS1);
  out_attn<<<(NN + 255) / 256, 256, 0, stream>>>(
      fQ1, fK1, fV1, fS1, iOffs + 3 * (NN + 1), iSE + (size_t)3 * EE, oWe, out);
}